// Round 2
// baseline (7916.970 us; speedup 1.0000x reference)
//
#include <hip/hip_runtime.h>

#define NN   16384
#define NE   262144
#define NB   32
#define H    128
#define NH   (NN*H)
#define RBF  50
#define TM   64
#define KC   64

__device__ __forceinline__ float sigmoidf_(float v){ return 1.0f/(1.0f + __expf(-v)); }
__device__ __forceinline__ float siluf_(float v){ return v * sigmoidf_(v); }

template<int ACT>
__device__ __forceinline__ float apply_act(float v){ return (ACT==1) ? siluf_(v) : v; }

// Inner 64-step K compute: 4 rows x 8 cols per thread.
#define GEMM_INNER(ACCVAR) \
  _Pragma("unroll 4") \
  for (int k=0;k<KC;k++){ \
    const float4 a  = *(const float4*)&As[k][r0]; \
    const float4 b0 = *(const float4*)&Ws[k][c0]; \
    const float4 b1 = *(const float4*)&Ws[k][c0+4]; \
    float av[4]={a.x,a.y,a.z,a.w}; \
    float bv[8]={b0.x,b0.y,b0.z,b0.w,b1.x,b1.y,b1.z,b1.w}; \
    _Pragma("unroll") \
    for(int ii=0;ii<4;ii++) \
      _Pragma("unroll") \
      for(int jj=0;jj<8;jj++) ACCVAR[ii][jj] = fmaf(av[ii], bv[jj], ACCVAR[ii][jj]); \
  }

// ---------------------------------------------------------------- zero
__global__ void k_zero(float* __restrict__ p, int n){
  int i = blockIdx.x*256 + threadIdx.x;
  if (i < n) p[i] = 0.f;
}

// ---------------------------------------------------------------- embed
__global__ void k_embed(const int* __restrict__ z, const float* __restrict__ emb,
                        float* __restrict__ x){
  int i = blockIdx.x*256 + threadIdx.x;
  int n = i >> 7, h = i & 127;
  x[i] = emb[z[n]*H + h];
}

// ---------------------------------------------------------------- ee1: fused RBF + GEMM(K=64,silu)
__global__ __launch_bounds__(256)
void k_ee1(const int* __restrict__ srcv, const int* __restrict__ dstv,
           const float* __restrict__ pos, const float* __restrict__ widths,
           const float* __restrict__ W, const float* __restrict__ bias,
           float* __restrict__ out){
  __shared__ __align__(16) float As[KC][TM+4];
  __shared__ __align__(16) float Ws[KC][H];
  __shared__ float dbuf[TM], cutv[TM];
  const int tid = threadIdx.x;
  const int tr = tid >> 4, tc = tid & 15;
  const int r0 = tr*4, c0 = tc*8;
  const int rowbase = blockIdx.x * TM;

  if (tid < TM){
    int e = rowbase + tid;
    int s = srcv[e], d = dstv[e];
    float dx = pos[3*d]   - pos[3*s];
    float dy = pos[3*d+1] - pos[3*s+1];
    float dz = pos[3*d+2] - pos[3*s+2];
    float dist = sqrtf(dx*dx + dy*dy + dz*dz);
    dbuf[tid] = dist;
    cutv[tid] = (dist < 5.0f) ? 0.5f*(__cosf(0.6283185307f*dist) + 1.0f) : 0.0f;
  }
#pragma unroll
  for (int i=0;i<KC*H/256;i++){
    int idx = tid + i*256; int k = idx >> 7, c = idx & 127;
    Ws[k][c] = (k < RBF) ? W[k*H + c] : 0.0f;
  }
  __syncthreads();
#pragma unroll
  for (int i=0;i<TM*KC/256;i++){
    int idx = tid + i*256; int k = idx & 63, r = idx >> 6;
    float v = 0.0f;
    if (k < RBF){
      float w = widths[k];
      float gamma = 1.0f/(2.0f*w*w);
      float t = dbuf[r] - 0.1020408163f*(float)k;   // centers: 5*k/49
      v = __expf(-gamma*t*t) * cutv[r];
    }
    As[k][r] = v;
  }
  __syncthreads();

  float acc[4][8];
#pragma unroll
  for (int i=0;i<4;i++)
#pragma unroll
    for (int j=0;j<8;j++) acc[i][j]=0.f;
  GEMM_INNER(acc)

#pragma unroll
  for (int i=0;i<4;i++){
    int row = rowbase + r0 + i;
    float4 o0, o1;
    o0.x = siluf_(acc[i][0]+bias[c0+0]); o0.y = siluf_(acc[i][1]+bias[c0+1]);
    o0.z = siluf_(acc[i][2]+bias[c0+2]); o0.w = siluf_(acc[i][3]+bias[c0+3]);
    o1.x = siluf_(acc[i][4]+bias[c0+4]); o1.y = siluf_(acc[i][5]+bias[c0+5]);
    o1.z = siluf_(acc[i][6]+bias[c0+6]); o1.w = siluf_(acc[i][7]+bias[c0+7]);
    *(float4*)&out[row*H + c0]   = o0;
    *(float4*)&out[row*H + c0+4] = o1;
  }
}

// ---------------------------------------------------------------- generic GEMM (A [rows,K] dense, in-place-safe)
template<int ACT>
__global__ __launch_bounds__(256)
void k_gemm(const float* __restrict__ A, int K,
            const float* __restrict__ W, const float* __restrict__ bias,
            float* __restrict__ out){
  __shared__ __align__(16) float As[KC][TM+4];
  __shared__ __align__(16) float Ws[KC][H];
  const int tid = threadIdx.x;
  const int tr = tid >> 4, tc = tid & 15;
  const int r0 = tr*4, c0 = tc*8;
  const int rowbase = blockIdx.x * TM;
  float acc[4][8];
#pragma unroll
  for (int i=0;i<4;i++)
#pragma unroll
    for (int j=0;j<8;j++) acc[i][j]=0.f;

  for (int kc=0; kc<K; kc+=KC){
    __syncthreads();
#pragma unroll
    for (int i=0;i<TM*KC/256;i++){
      int idx = tid + i*256; int k = idx & 63, r = idx >> 6;
      As[k][r] = A[(size_t)(rowbase + r)*K + kc + k];
    }
#pragma unroll
    for (int i=0;i<KC*H/256;i++){
      int idx = tid + i*256; int k = idx >> 7, c = idx & 127;
      Ws[k][c] = W[(kc + k)*H + c];
    }
    __syncthreads();
    GEMM_INNER(acc)
  }
#pragma unroll
  for (int i=0;i<4;i++){
    int row = rowbase + r0 + i;
    float4 o0, o1;
    o0.x = apply_act<ACT>(acc[i][0]+bias[c0+0]); o0.y = apply_act<ACT>(acc[i][1]+bias[c0+1]);
    o0.z = apply_act<ACT>(acc[i][2]+bias[c0+2]); o0.w = apply_act<ACT>(acc[i][3]+bias[c0+3]);
    o1.x = apply_act<ACT>(acc[i][4]+bias[c0+4]); o1.y = apply_act<ACT>(acc[i][5]+bias[c0+5]);
    o1.z = apply_act<ACT>(acc[i][6]+bias[c0+6]); o1.w = apply_act<ACT>(acc[i][7]+bias[c0+7]);
    *(float4*)&out[(size_t)row*H + c0]   = o0;
    *(float4*)&out[(size_t)row*H + c0+4] = o1;
  }
}

// ---------------------------------------------------------------- msg1: concat(x[dst],x[src],ee) @ W (K=384), silu
__global__ __launch_bounds__(256)
void k_msg1(const float* __restrict__ x, const float* __restrict__ ee,
            const int* __restrict__ srcv, const int* __restrict__ dstv,
            const float* __restrict__ W, const float* __restrict__ bias,
            float* __restrict__ out){
  __shared__ __align__(16) float As[KC][TM+4];
  __shared__ __align__(16) float Ws[KC][H];
  __shared__ int gidx[2][TM];
  const int tid = threadIdx.x;
  const int tr = tid >> 4, tc = tid & 15;
  const int r0 = tr*4, c0 = tc*8;
  const int rowbase = blockIdx.x * TM;
  if (tid < TM)        gidx[0][tid]     = dstv[rowbase + tid];
  else if (tid < 2*TM) gidx[1][tid-TM]  = srcv[rowbase + tid - TM];

  float acc[4][8];
#pragma unroll
  for (int i=0;i<4;i++)
#pragma unroll
    for (int j=0;j<8;j++) acc[i][j]=0.f;

  for (int kc=0; kc<3*H; kc+=KC){
    const int part = kc >> 7;
    const int kl   = kc & 127;
    __syncthreads();
#pragma unroll
    for (int i=0;i<TM*KC/256;i++){
      int idx = tid + i*256; int k = idx & 63, r = idx >> 6;
      float v;
      if (part == 0)      v = x[gidx[0][r]*H + kl + k];
      else if (part == 1) v = x[gidx[1][r]*H + kl + k];
      else                v = ee[(size_t)(rowbase + r)*H + kl + k];
      As[k][r] = v;
    }
#pragma unroll
    for (int i=0;i<KC*H/256;i++){
      int idx = tid + i*256; int k = idx >> 7, c = idx & 127;
      Ws[k][c] = W[(kc + k)*H + c];
    }
    __syncthreads();
    GEMM_INNER(acc)
  }
#pragma unroll
  for (int i=0;i<4;i++){
    int row = rowbase + r0 + i;
    float4 o0, o1;
    o0.x = siluf_(acc[i][0]+bias[c0+0]); o0.y = siluf_(acc[i][1]+bias[c0+1]);
    o0.z = siluf_(acc[i][2]+bias[c0+2]); o0.w = siluf_(acc[i][3]+bias[c0+3]);
    o1.x = siluf_(acc[i][4]+bias[c0+4]); o1.y = siluf_(acc[i][5]+bias[c0+5]);
    o1.z = siluf_(acc[i][6]+bias[c0+6]); o1.w = siluf_(acc[i][7]+bias[c0+7]);
    *(float4*)&out[(size_t)row*H + c0]   = o0;
    *(float4*)&out[(size_t)row*H + c0+4] = o1;
  }
}

// ---------------------------------------------------------------- msg2 + gate + atomic aggregation
__global__ __launch_bounds__(256)
void k_msg2(const float* __restrict__ hbuf, const float* __restrict__ eebuf,
            const int* __restrict__ dstv,
            const float* __restrict__ W2, const float* __restrict__ b2,
            const float* __restrict__ Wg, const float* __restrict__ bg,
            float* __restrict__ aggr){
  __shared__ __align__(16) float As[KC][TM+4];
  __shared__ __align__(16) float Ws[KC][H];
  const int tid = threadIdx.x;
  const int tr = tid >> 4, tc = tid & 15;
  const int r0 = tr*4, c0 = tc*8;
  const int rowbase = blockIdx.x * TM;
  float acc[2][4][8];
#pragma unroll
  for (int p=0;p<2;p++)
#pragma unroll
    for (int i=0;i<4;i++)
#pragma unroll
      for (int j=0;j<8;j++) acc[p][i][j]=0.f;

#pragma unroll
  for (int ph=0; ph<2; ph++){
    const float* Ap = ph ? eebuf : hbuf;
    const float* Wp = ph ? Wg : W2;
    for (int kc=0; kc<H; kc+=KC){
      __syncthreads();
#pragma unroll
      for (int i=0;i<TM*KC/256;i++){
        int idx = tid + i*256; int k = idx & 63, r = idx >> 6;
        As[k][r] = Ap[(size_t)(rowbase + r)*H + kc + k];
      }
#pragma unroll
      for (int i=0;i<KC*H/256;i++){
        int idx = tid + i*256; int k = idx >> 7, c = idx & 127;
        Ws[k][c] = Wp[(kc + k)*H + c];
      }
      __syncthreads();
      GEMM_INNER(acc[ph])
    }
  }
#pragma unroll
  for (int i=0;i<4;i++){
    int e = rowbase + r0 + i;
    int dn = dstv[e];
    float* arow = aggr + (size_t)dn*H;
#pragma unroll
    for (int j=0;j<8;j++){
      float m  = acc[0][i][j] + b2[c0+j];
      float gt = sigmoidf_(acc[1][i][j] + bg[c0+j]);
      atomicAdd(&arow[c0+j], m*gt);
    }
  }
}

// ---------------------------------------------------------------- upd1: concat(aggr,x) @ W (K=256), silu
template<int ACT>
__global__ __launch_bounds__(256)
void k_gemm_cat2(const float* __restrict__ A0, const float* __restrict__ A1,
                 const float* __restrict__ W, const float* __restrict__ bias,
                 float* __restrict__ out){
  __shared__ __align__(16) float As[KC][TM+4];
  __shared__ __align__(16) float Ws[KC][H];
  const int tid = threadIdx.x;
  const int tr = tid >> 4, tc = tid & 15;
  const int r0 = tr*4, c0 = tc*8;
  const int rowbase = blockIdx.x * TM;
  float acc[4][8];
#pragma unroll
  for (int i=0;i<4;i++)
#pragma unroll
    for (int j=0;j<8;j++) acc[i][j]=0.f;

  for (int kc=0; kc<2*H; kc+=KC){
    const float* Ap = (kc >> 7) ? A1 : A0;
    const int kl = kc & 127;
    __syncthreads();
#pragma unroll
    for (int i=0;i<TM*KC/256;i++){
      int idx = tid + i*256; int k = idx & 63, r = idx >> 6;
      As[k][r] = Ap[(rowbase + r)*H + kl + k];
    }
#pragma unroll
    for (int i=0;i<KC*H/256;i++){
      int idx = tid + i*256; int k = idx >> 7, c = idx & 127;
      Ws[k][c] = W[(kc + k)*H + c];
    }
    __syncthreads();
    GEMM_INNER(acc)
  }
#pragma unroll
  for (int i=0;i<4;i++){
    int row = rowbase + r0 + i;
    float4 o0, o1;
    o0.x = apply_act<ACT>(acc[i][0]+bias[c0+0]); o0.y = apply_act<ACT>(acc[i][1]+bias[c0+1]);
    o0.z = apply_act<ACT>(acc[i][2]+bias[c0+2]); o0.w = apply_act<ACT>(acc[i][3]+bias[c0+3]);
    o1.x = apply_act<ACT>(acc[i][4]+bias[c0+4]); o1.y = apply_act<ACT>(acc[i][5]+bias[c0+5]);
    o1.z = apply_act<ACT>(acc[i][6]+bias[c0+6]); o1.w = apply_act<ACT>(acc[i][7]+bias[c0+7]);
    *(float4*)&out[row*H + c0]   = o0;
    *(float4*)&out[row*H + c0+4] = o1;
  }
}

// ---------------------------------------------------------------- upd2 + residual + LayerNorm (+sum into af)
template<int ADDSUM>
__global__ __launch_bounds__(256)
void k_upd2_ln(const float* __restrict__ hn, const float* __restrict__ W,
               const float* __restrict__ b2, const float* __restrict__ lng,
               const float* __restrict__ lnb, float* __restrict__ x,
               float* __restrict__ sumf){
  __shared__ __align__(16) float Ws[KC][H];
  __shared__ float As[16][H+1];
  const int tid = threadIdx.x;
  const int row = tid >> 4, cg = tid & 15, c0 = cg*8;
  const int rowbase = blockIdx.x * 16;
#pragma unroll
  for (int i=0;i<16*H/256;i++){
    int idx = tid + i*256; int r = idx >> 7, k = idx & 127;
    As[r][k] = hn[(rowbase + r)*H + k];
  }
  float acc[8] = {0,0,0,0,0,0,0,0};
  for (int kc=0; kc<H; kc+=KC){
#pragma unroll
    for (int i=0;i<KC*H/256;i++){
      int idx = tid + i*256; int k = idx >> 7, c = idx & 127;
      Ws[k][c] = W[(kc + k)*H + c];
    }
    __syncthreads();
#pragma unroll 4
    for (int k=0;k<KC;k++){
      float a = As[row][kc+k];
      const float4 w0 = *(const float4*)&Ws[k][c0];
      const float4 w1 = *(const float4*)&Ws[k][c0+4];
      acc[0]=fmaf(a,w0.x,acc[0]); acc[1]=fmaf(a,w0.y,acc[1]);
      acc[2]=fmaf(a,w0.z,acc[2]); acc[3]=fmaf(a,w0.w,acc[3]);
      acc[4]=fmaf(a,w1.x,acc[4]); acc[5]=fmaf(a,w1.y,acc[5]);
      acc[6]=fmaf(a,w1.z,acc[6]); acc[7]=fmaf(a,w1.w,acc[7]);
    }
    __syncthreads();
  }
  const int ro = (rowbase + row)*H;
  float y[8]; float s=0.f, ss=0.f;
#pragma unroll
  for (int j=0;j<8;j++){ y[j] = x[ro+c0+j] + acc[j] + b2[c0+j]; s += y[j]; ss += y[j]*y[j]; }
#pragma unroll
  for (int m=8;m>=1;m>>=1){ s += __shfl_xor(s,m,16); ss += __shfl_xor(ss,m,16); }
  float mean = s*(1.0f/H);
  float var  = ss*(1.0f/H) - mean*mean;
  float inv  = rsqrtf(var + 1e-5f);
#pragma unroll
  for (int j=0;j<8;j++){
    float o = (y[j]-mean)*inv*lng[c0+j] + lnb[c0+j];
    x[ro+c0+j] = o;
    if (ADDSUM) sumf[ro+c0+j] += o;
  }
}

// ---------------------------------------------------------------- af = sum/3 (in place safe)
__global__ void k_af(const float* __restrict__ s, float* __restrict__ o){
  int i = blockIdx.x*256 + threadIdx.x;
  o[i] = s[i]*(1.0f/3.0f);
}

// ---------------------------------------------------------------- gate score g[n]
__global__ __launch_bounds__(256)
void k_gscore(const float* __restrict__ ae, const float* __restrict__ W1,
              const float* __restrict__ b1, const float* __restrict__ w2,
              const float* __restrict__ b2, float* __restrict__ g){
  __shared__ __align__(16) float Ws[KC][H];
  __shared__ float As[16][H+1];
  const int tid = threadIdx.x;
  const int row = tid >> 4, cg = tid & 15, c0 = cg*8;
  const int rowbase = blockIdx.x * 16;
#pragma unroll
  for (int i=0;i<16*H/256;i++){
    int idx = tid + i*256; int r = idx >> 7, k = idx & 127;
    As[r][k] = ae[(rowbase + r)*H + k];
  }
  float acc[8] = {0,0,0,0,0,0,0,0};
  for (int kc=0; kc<H; kc+=KC){
#pragma unroll
    for (int i=0;i<KC*H/256;i++){
      int idx = tid + i*256; int k = idx >> 7, c = idx & 127;
      Ws[k][c] = W1[(kc + k)*H + c];
    }
    __syncthreads();
#pragma unroll 4
    for (int k=0;k<KC;k++){
      float a = As[row][kc+k];
      const float4 w0 = *(const float4*)&Ws[k][c0];
      const float4 w1 = *(const float4*)&Ws[k][c0+4];
      acc[0]=fmaf(a,w0.x,acc[0]); acc[1]=fmaf(a,w0.y,acc[1]);
      acc[2]=fmaf(a,w0.z,acc[2]); acc[3]=fmaf(a,w0.w,acc[3]);
      acc[4]=fmaf(a,w1.x,acc[4]); acc[5]=fmaf(a,w1.y,acc[5]);
      acc[6]=fmaf(a,w1.z,acc[6]); acc[7]=fmaf(a,w1.w,acc[7]);
    }
    __syncthreads();
  }
  float p = 0.f;
#pragma unroll
  for (int j=0;j<8;j++) p = fmaf(tanhf(acc[j] + b1[c0+j]), w2[c0+j], p);
#pragma unroll
  for (int m=8;m>=1;m>>=1) p += __shfl_xor(p,m,16);
  if (cg == 0) g[rowbase + row] = p + b2[0];
}

// ---------------------------------------------------------------- segment starts (batch sorted)
__global__ void k_start(const int* __restrict__ batch, int* __restrict__ start){
  int b = threadIdx.x;
  if (b > NB) return;
  if (b == NB){ start[NB] = NN; return; }
  int lo = 0, hi = NN;
  while (lo < hi){ int mid = (lo+hi) >> 1; if (batch[mid] < b) lo = mid+1; else hi = mid; }
  start[b] = lo;
}

// ---------------------------------------------------------------- attentional pooling per graph
__global__ __launch_bounds__(256)
void k_pool(const int* __restrict__ start, const float* __restrict__ g,
            float* __restrict__ exb, const float* __restrict__ h,
            float* __restrict__ out){
  const int b = blockIdx.x;
  const int s = start[b], e = start[b+1];
  const int tid = threadIdx.x;
  __shared__ float red[4];
  __shared__ float s_gmax, s_den;
  __shared__ float part[2][H];

  float mx = -1e30f;
  for (int n = s + tid; n < e; n += 256) mx = fmaxf(mx, g[n]);
#pragma unroll
  for (int m=32;m>=1;m>>=1) mx = fmaxf(mx, __shfl_xor(mx, m, 64));
  if ((tid & 63) == 0) red[tid >> 6] = mx;
  __syncthreads();
  if (tid == 0){
    float v = fmaxf(fmaxf(red[0],red[1]), fmaxf(red[2],red[3]));
    s_gmax = (e > s) ? v : 0.0f;
  }
  __syncthreads();
  const float gmax = s_gmax;

  float sum = 0.f;
  for (int n = s + tid; n < e; n += 256){
    float ex = __expf(g[n] - gmax);
    exb[n] = ex;
    sum += ex;
  }
#pragma unroll
  for (int m=32;m>=1;m>>=1) sum += __shfl_xor(sum, m, 64);
  if ((tid & 63) == 0) red[tid >> 6] = sum;
  __syncthreads();
  if (tid == 0) s_den = red[0]+red[1]+red[2]+red[3];
  __syncthreads();
  const float den = s_den;

  const int col = tid & 127, rg = tid >> 7;
  float acc = 0.f;
  for (int n = s + rg; n < e; n += 2) acc = fmaf(exb[n], h[n*H + col], acc);
  part[rg][col] = acc;
  __syncthreads();
  if (tid < H){
    float v = part[0][tid] + part[1][tid];
    out[b*H + tid] = (den > 0.f) ? v/den : 0.0f;
  }
}

// ================================================================ host
extern "C" void kernel_launch(void* const* d_in, const int* in_sizes, int n_in,
                              void* d_out, int out_size, void* d_ws, size_t ws_size,
                              hipStream_t stream){
  const int*   Z      = (const int*)  d_in[0];
  const float* pos    = (const float*)d_in[1];
  const int*   batch  = (const int*)  d_in[2];
  const int*   ei     = (const int*)  d_in[3];
  const float* embed  = (const float*)d_in[4];
  const float* widths = (const float*)d_in[5];
  const float* ee_w1  = (const float*)d_in[6];
  const float* ee_b1  = (const float*)d_in[7];
  const float* ee_w2  = (const float*)d_in[8];
  const float* ee_b2  = (const float*)d_in[9];
  const float* msg_w1 = (const float*)d_in[10];
  const float* msg_b1 = (const float*)d_in[11];
  const float* msg_w2 = (const float*)d_in[12];
  const float* msg_b2 = (const float*)d_in[13];
  const float* gate_w = (const float*)d_in[14];
  const float* gate_b = (const float*)d_in[15];
  const float* upd_w1 = (const float*)d_in[16];
  const float* upd_b1 = (const float*)d_in[17];
  const float* upd_w2 = (const float*)d_in[18];
  const float* upd_b2 = (const float*)d_in[19];
  const float* ln_g   = (const float*)d_in[20];
  const float* ln_b   = (const float*)d_in[21];
  const float* gp_w1  = (const float*)d_in[22];
  const float* gp_b1  = (const float*)d_in[23];
  const float* gp_w2  = (const float*)d_in[24];
  const float* gp_b2  = (const float*)d_in[25];
  const float* pn_w   = (const float*)d_in[26];
  const float* pn_b   = (const float*)d_in[27];
  const float* ro_w1  = (const float*)d_in[28];
  const float* ro_b1  = (const float*)d_in[29];
  const float* ro_w2  = (const float*)d_in[30];
  const float* ro_b2  = (const float*)d_in[31];

  const int* srcv = ei;
  const int* dstv = ei + NE;

  // ---- workspace layout (adaptive edge chunking so we never exceed ws_size)
  float* ws   = (float*)d_ws;
  float* x    = ws;                       // NH
  float* aggr = x + NH;                   // NH
  float* hn   = aggr + NH;                // NH
  float* gsc  = hn + NH;                  // NN
  float* exb  = gsc + NN;                 // NN
  int*   startb = (int*)(exb + NN);       // 64 slots
  float* bufA = exb + NN + 64;            // chunk ee buffer
  const size_t fixedf = (size_t)NH*3 + (size_t)NN*2 + 64;

  int NC = 1;
  while (NC < 256){
    size_t needf = fixedf + 2*((size_t)NE/NC)*H;
    if (needf*sizeof(float) <= ws_size) break;
    NC <<= 1;
  }
  const int CH = NE / NC;                 // edges per chunk
  float* bufB = bufA + (size_t)CH*H;

  float* out_af  = (float*)d_out;         // also the running sum of last-3 feats
  float* out_ae  = out_af + NH;
  float* out_gaf = out_ae + NH;

  k_embed<<<NH/256, 256, 0, stream>>>(Z, embed, x);
  k_zero<<<NH/256, 256, 0, stream>>>(out_af, NH);

  for (int l=0; l<4; l++){
    k_zero<<<NH/256, 256, 0, stream>>>(aggr, NH);
    for (int c=0; c<NC; c++){
      const int eo = c*CH;
      k_ee1<<<CH/TM, 256, 0, stream>>>(srcv+eo, dstv+eo, pos, widths,
                                       ee_w1 + l*RBF*H, ee_b1 + l*H, bufA);
      k_gemm<0><<<CH/TM, 256, 0, stream>>>(bufA, H, ee_w2 + l*H*H, ee_b2 + l*H, bufA); // in-place: ee
      k_msg1<<<CH/TM, 256, 0, stream>>>(x, bufA, srcv+eo, dstv+eo,
                                        msg_w1 + l*3*H*H, msg_b1 + l*H, bufB);
      k_msg2<<<CH/TM, 256, 0, stream>>>(bufB, bufA, dstv+eo,
                                        msg_w2 + l*H*H, msg_b2 + l*H,
                                        gate_w + l*H*H, gate_b + l*H, aggr);
    }
    k_gemm_cat2<1><<<NN/TM, 256, 0, stream>>>(aggr, x,
                                              upd_w1 + l*2*H*H, upd_b1 + l*H, hn);
    if (l == 0)
      k_upd2_ln<0><<<NN/16, 256, 0, stream>>>(hn, upd_w2 + l*H*H, upd_b2 + l*H,
                                              ln_g + l*H, ln_b + l*H, x, out_af);
    else
      k_upd2_ln<1><<<NN/16, 256, 0, stream>>>(hn, upd_w2 + l*H*H, upd_b2 + l*H,
                                              ln_g + l*H, ln_b + l*H, x, out_af);
  }

  k_af<<<NH/256, 256, 0, stream>>>(out_af, out_af);
  k_gemm<1><<<NN/TM, 256, 0, stream>>>(out_af, H, ro_w1, ro_b1, hn);
  k_gemm<0><<<NN/TM, 256, 0, stream>>>(hn, H, ro_w2, ro_b2, out_ae);
  k_gscore<<<NN/16, 256, 0, stream>>>(out_ae, gp_w1, gp_b1, gp_w2, gp_b2, gsc);
  k_gemm<1><<<NN/TM, 256, 0, stream>>>(out_ae, H, pn_w, pn_b, hn);
  k_start<<<1, 64, 0, stream>>>(batch, startb);
  k_pool<<<NB, 256, 0, stream>>>(startb, gsc, exb, hn, out_gaf);
}

// Round 3
// 1756.278 us; speedup vs baseline: 4.5078x; 4.5078x over previous
//
#include <hip/hip_runtime.h>

#define NN   16384
#define NE   262144
#define NB   32
#define H    128
#define NH   (NN*H)
#define RBF  50
#define TM   64
#define KC   64
#define KP   72     // KC + 8 bf16 pad (row pitch 144 B, non-pow2 banks)
#define HBP  136    // Hb pitch (272 B)
#define LT   106496 // packed weights per layer (u16 elems)

typedef unsigned short u16;
typedef short bf16x8 __attribute__((ext_vector_type(8)));
typedef float f32x4 __attribute__((ext_vector_type(4)));

__device__ __forceinline__ float sigmoidf_(float v){ return 1.0f/(1.0f + __expf(-v)); }
__device__ __forceinline__ float siluf_(float v){ return v * sigmoidf_(v); }
__device__ __forceinline__ u16 f2bf(float f){
  unsigned u = __float_as_uint(f);
  return (u16)((u + 0x7FFFu + ((u>>16)&1u)) >> 16);
}
__device__ __forceinline__ float bf2f(u16 v){ return __uint_as_float(((unsigned)v)<<16); }

template<int ACT>
__device__ __forceinline__ float apply_act(float v){ return (ACT==1) ? siluf_(v) : v; }

// ---- MFMA helpers (all use: tid, wrow, l15, q8 from scope) ----
// stage weight chunk [128][KC] from packed global (row-major [128][kpad]) into Wt
#define STAGE_WT(GSRC, KPAD, K0) \
  _Pragma("unroll") \
  for (int i_=0;i_<4;i_++){ \
    int o_ = tid + i_*256; \
    int c_ = o_ >> 3, ko_ = (o_ & 7)*8; \
    *(uint4*)&Wt[c_][ko_] = *(const uint4*)((GSRC) + (size_t)c_*(KPAD) + (K0) + ko_); \
  }

// stage A chunk [64][KC] from per-row u16 pointers; ROWPTR uses r_
#define STAGE_AB(ROWPTR) \
  _Pragma("unroll") \
  for (int i_=0;i_<2;i_++){ \
    int o_ = tid*2 + i_; \
    int r_ = o_ >> 3, ko_ = (o_ & 7)*8; \
    const u16* rp_ = (ROWPTR); \
    *(uint4*)&Ab[r_][ko_] = *(const uint4*)(rp_ + ko_); \
  }

// one KC(=64) K-chunk of MFMA over 8 col-tiles
#define MFMA_TILES(ABUF, KOFF, ACC) \
  _Pragma("unroll") \
  for (int ks_=0; ks_<KC; ks_+=32){ \
    bf16x8 af_ = *(const bf16x8*)&ABUF[wrow + l15][(KOFF) + ks_ + q8]; \
    _Pragma("unroll") \
    for (int t_=0;t_<8;t_++){ \
      bf16x8 bf_ = *(const bf16x8*)&Wt[t_*16 + l15][ks_ + q8]; \
      ACC[t_] = __builtin_amdgcn_mfma_f32_16x16x32_bf16(af_, bf_, ACC[t_], 0, 0, 0); \
    } \
  }

// ---------------------------------------------------------------- utility
__global__ void k_zero(float* __restrict__ p, int n){
  int i = blockIdx.x*256 + threadIdx.x; if (i < n) p[i] = 0.f;
}
__global__ void k_zero_i(int* __restrict__ p, int n){
  int i = blockIdx.x*256 + threadIdx.x; if (i < n) p[i] = 0;
}
__global__ void k_embed(const int* __restrict__ z, const float* __restrict__ emb,
                        float* __restrict__ x, u16* __restrict__ xb){
  int i = blockIdx.x*256 + threadIdx.x;
  int n = i >> 7, h = i & 127;
  float v = emb[z[n]*H + h];
  x[i] = v; xb[i] = f2bf(v);
}
__global__ void k_af(const float* __restrict__ s, float* __restrict__ o){
  int i = blockIdx.x*256 + threadIdx.x;
  o[i] = s[i]*(1.0f/3.0f);
}

// ---------------------------------------------------------------- weight pack (f32 [K][128] -> bf16 [128][Kpad])
__global__ void k_pack(const float* __restrict__ ee_w1, const float* __restrict__ ee_w2,
                       const float* __restrict__ msg_w1, const float* __restrict__ msg_w2,
                       const float* __restrict__ gate_w, u16* __restrict__ out){
  int idx = blockIdx.x*256 + threadIdx.x;
  int l = blockIdx.y;
  if (idx >= LT) return;
  u16* o = out + (size_t)l*LT;
  float v; int c, k;
  if (idx < 8192){            c = idx>>6;  k = idx&63;
    v = (k<RBF) ? ee_w1[(size_t)l*RBF*H + k*H + c] : 0.f; }
  else if (idx < 24576){ int j=idx-8192;  c=j>>7; k=j&127;
    v = ee_w2[(size_t)l*H*H + k*H + c]; }
  else if (idx < 73728){ int j=idx-24576; c=j/384; k=j%384;
    v = msg_w1[(size_t)l*3*H*H + k*H + c]; }
  else if (idx < 90112){ int j=idx-73728; c=j>>7; k=j&127;
    v = msg_w2[(size_t)l*H*H + k*H + c]; }
  else {                 int j=idx-90112; c=j>>7; k=j&127;
    v = gate_w[(size_t)l*H*H + k*H + c]; }
  o[idx] = f2bf(v);
}

// ---------------------------------------------------------------- edge sort by dst (counting sort)
__global__ void k_hist(const int* __restrict__ dstv, int* __restrict__ cnt){
  int e = blockIdx.x*256 + threadIdx.x;
  if (e < NE) atomicAdd(&cnt[dstv[e]], 1);
}
__global__ __launch_bounds__(1024)
void k_scan(int* __restrict__ cnt /* in: counts, out: cursor */, int* __restrict__ start){
  __shared__ int ps[1024];
  int tid = threadIdx.x;
  int base = tid*16;
  int loc[16]; int s = 0;
#pragma unroll
  for (int i=0;i<16;i++){ loc[i] = s; s += cnt[base+i]; }
  ps[tid] = s; __syncthreads();
  for (int off=1; off<1024; off<<=1){
    int v = (tid>=off) ? ps[tid-off] : 0;
    __syncthreads();
    ps[tid] += v;
    __syncthreads();
  }
  int pre = (tid>0) ? ps[tid-1] : 0;
#pragma unroll
  for (int i=0;i<16;i++){ int v = pre + loc[i]; start[base+i] = v; cnt[base+i] = v; }
  if (tid == 0) start[NN] = NE;
}
__global__ void k_scatter(const int* __restrict__ srcv, const int* __restrict__ dstv,
                          int* __restrict__ cursor, int* __restrict__ src_s,
                          int* __restrict__ dst_s){
  int e = blockIdx.x*256 + threadIdx.x;
  if (e >= NE) return;
  int d = dstv[e];
  int p = atomicAdd(&cursor[d], 1);
  src_s[p] = srcv[e]; dst_s[p] = d;
}

// ---------------------------------------------------------------- fused ee MLP: RBF -> GEMM(K=64,silu) -> GEMM(K=128)
__global__ __launch_bounds__(256)
void k_ee(const int* __restrict__ srcv, const int* __restrict__ dstv,
          const float* __restrict__ pos, const float* __restrict__ widths,
          const u16* __restrict__ w1t, const float* __restrict__ b1,
          const u16* __restrict__ w2t, const float* __restrict__ b2,
          u16* __restrict__ outEE){
  __shared__ u16 Ab[TM][KP];
  __shared__ u16 Wt[H][KP];
  __shared__ u16 Hb[TM][HBP];
  __shared__ float dls[TM], cls[TM], gls[KC], bls[H];
  const int tid = threadIdx.x;
  const int wave = tid>>6, l = tid&63, l15 = l&15, quad = l>>4;
  const int wrow = wave*16, q8 = quad*8;
  const int rowbase = blockIdx.x*TM;

  STAGE_WT(w1t, 64, 0)
  if (tid < TM){
    int e = rowbase + tid;
    int s = srcv[e], d = dstv[e];
    float dx = pos[3*d]-pos[3*s], dy = pos[3*d+1]-pos[3*s+1], dz = pos[3*d+2]-pos[3*s+2];
    float dist = sqrtf(dx*dx + dy*dy + dz*dz);
    dls[tid] = dist;
    cls[tid] = (dist < 5.0f) ? 0.5f*(__cosf(0.62831853f*dist) + 1.0f) : 0.0f;
  } else if (tid < TM+KC){
    int k = tid - TM;
    float w = (k < RBF) ? widths[k] : 1.0f;
    gls[k] = 1.0f/(2.0f*w*w);
  } else if (tid < TM+KC+H){
    bls[tid-TM-KC] = b1[tid-TM-KC];
  }
  __syncthreads();
  { // RBF fill: thread -> row tid>>2, 16 k's
    int r = tid>>2, kb = (tid&3)*16;
    float dr = dls[r], cr = cls[r];
#pragma unroll
    for (int kk=0; kk<16; kk+=2){
      int k0 = kb+kk, k1 = kb+kk+1;
      float t0 = dr - 0.10204082f*(float)k0;
      float t1 = dr - 0.10204082f*(float)k1;
      float v0 = (k0 < RBF) ? __expf(-gls[k0]*t0*t0)*cr : 0.f;
      float v1 = (k1 < RBF) ? __expf(-gls[k1]*t1*t1)*cr : 0.f;
      *(unsigned*)&Ab[r][k0] = (unsigned)f2bf(v0) | ((unsigned)f2bf(v1)<<16);
    }
  }
  __syncthreads();

  f32x4 acc1[8];
#pragma unroll
  for (int t=0;t<8;t++) acc1[t] = (f32x4)(0.f);
  MFMA_TILES(Ab, 0, acc1)

  // hidden (silu) -> Hb
#pragma unroll
  for (int t=0;t<8;t++){
    int col = t*16 + l15;
    float b = bls[col];
#pragma unroll
    for (int r=0;r<4;r++){
      int gr = wrow + quad*4 + r;
      Hb[gr][col] = f2bf(siluf_(acc1[t][r] + b));
    }
  }

  f32x4 acc2[8];
#pragma unroll
  for (int t=0;t<8;t++) acc2[t] = (f32x4)(0.f);
  for (int kc=0; kc<H; kc+=KC){
    __syncthreads();
    STAGE_WT(w2t, 128, kc)
    if (kc == 0 && tid < H) bls[tid] = b2[tid];
    __syncthreads();
    MFMA_TILES(Hb, kc, acc2)
  }
#pragma unroll
  for (int t=0;t<8;t++){
    int col = t*16 + l15;
    float b = bls[col];
#pragma unroll
    for (int r=0;r<4;r++){
      int gr = wrow + quad*4 + r;
      outEE[(size_t)(rowbase+gr)*H + col] = f2bf(acc2[t][r] + b);
    }
  }
}

// ---------------------------------------------------------------- msg1: concat(x[dst],x[src],ee) @ W (K=384), silu
__global__ __launch_bounds__(256)
void k_msg1(const u16* __restrict__ xb, const u16* __restrict__ ee,
            const int* __restrict__ srcv, const int* __restrict__ dstv,
            const u16* __restrict__ w1t, const float* __restrict__ b1,
            u16* __restrict__ outM){
  __shared__ u16 Ab[TM][KP];
  __shared__ u16 Wt[H][KP];
  __shared__ int gidx[2][TM];
  __shared__ float bls[H];
  const int tid = threadIdx.x;
  const int wave = tid>>6, l = tid&63, l15 = l&15, quad = l>>4;
  const int wrow = wave*16, q8 = quad*8;
  const int rowbase = blockIdx.x*TM;
  if (tid < TM)        gidx[0][tid]    = dstv[rowbase + tid];
  else if (tid < 2*TM) gidx[1][tid-TM] = srcv[rowbase + tid - TM];
  else if (tid < 2*TM + H) bls[tid-2*TM] = b1[tid-2*TM];

  f32x4 acc[8];
#pragma unroll
  for (int t=0;t<8;t++) acc[t] = (f32x4)(0.f);

  for (int kc=0; kc<6; kc++){
    __syncthreads();
    if (kc < 2)      { const int kl = kc*64;     STAGE_AB(xb + (size_t)gidx[0][r_]*H + kl) }
    else if (kc < 4) { const int kl = (kc-2)*64; STAGE_AB(xb + (size_t)gidx[1][r_]*H + kl) }
    else             { const int kl = (kc-4)*64; STAGE_AB(ee + (size_t)(rowbase + r_)*H + kl) }
    STAGE_WT(w1t, 384, kc*64)
    __syncthreads();
    MFMA_TILES(Ab, 0, acc)
  }
#pragma unroll
  for (int t=0;t<8;t++){
    int col = t*16 + l15;
    float b = bls[col];
#pragma unroll
    for (int r=0;r<4;r++){
      int gr = wrow + quad*4 + r;
      outM[(size_t)(rowbase+gr)*H + col] = f2bf(siluf_(acc[t][r] + b));
    }
  }
}

// ---------------------------------------------------------------- msg2: (msg@W2 + b2) * sigmoid(ee@Wg + bg) -> in-place bf16
__global__ __launch_bounds__(256)
void k_msg2(u16* __restrict__ msgb, const u16* __restrict__ eeb,
            const u16* __restrict__ w2t, const float* __restrict__ b2,
            const u16* __restrict__ wgt, const float* __restrict__ bg){
  __shared__ u16 Ab[TM][KP];
  __shared__ u16 Wt[H][KP];
  __shared__ float b2ls[H], bgls[H];
  const int tid = threadIdx.x;
  const int wave = tid>>6, l = tid&63, l15 = l&15, quad = l>>4;
  const int wrow = wave*16, q8 = quad*8;
  const int rowbase = blockIdx.x*TM;
  if (tid < H) b2ls[tid] = b2[tid];
  else if (tid < 2*H) bgls[tid-H] = bg[tid-H];

  f32x4 accm[8], accg[8];
#pragma unroll
  for (int t=0;t<8;t++){ accm[t] = (f32x4)(0.f); accg[t] = (f32x4)(0.f); }

#pragma unroll
  for (int ph=0; ph<2; ph++){
    const u16* Ap = ph ? eeb : msgb;
    const u16* Wp = ph ? wgt : w2t;
    f32x4* ACC = ph ? accg : accm;
    for (int kc=0; kc<H; kc+=KC){
      __syncthreads();
      STAGE_AB(Ap + (size_t)(rowbase + r_)*H + kc)
      STAGE_WT(Wp, 128, kc)
      __syncthreads();
      MFMA_TILES(Ab, 0, ACC)
    }
  }
#pragma unroll
  for (int t=0;t<8;t++){
    int col = t*16 + l15;
    float bm = b2ls[col], bgv = bgls[col];
#pragma unroll
    for (int r=0;r<4;r++){
      int gr = wrow + quad*4 + r;
      float m  = accm[t][r] + bm;
      float gt = sigmoidf_(accg[t][r] + bgv);
      msgb[(size_t)(rowbase+gr)*H + col] = f2bf(m*gt);
    }
  }
}

// ---------------------------------------------------------------- segmented aggregation (edges sorted by dst; no atomics)
__global__ __launch_bounds__(256)
void k_aggr(const int* __restrict__ estart, const u16* __restrict__ gm,
            int eo, int ch, float* __restrict__ aggr){
  int n   = blockIdx.x*2 + (threadIdx.x >> 7);
  int col = threadIdx.x & 127;
  int s = estart[n], e = estart[n+1];
  s = max(s, eo); e = min(e, eo + ch);
  if (s >= e) return;
  float acc = 0.f;
  for (int p=s; p<e; p++) acc += bf2f(gm[(size_t)(p-eo)*H + col]);
  aggr[(size_t)n*H + col] += acc;
}

// ---------------------------------------------------------------- f32 node-side kernels (small: N=16384)
#define GEMM_INNER(ACCVAR) \
  _Pragma("unroll 4") \
  for (int k=0;k<KC;k++){ \
    const float4 a  = *(const float4*)&As[k][r0]; \
    const float4 b0 = *(const float4*)&Ws[k][c0]; \
    const float4 b1v = *(const float4*)&Ws[k][c0+4]; \
    float av[4]={a.x,a.y,a.z,a.w}; \
    float bv[8]={b0.x,b0.y,b0.z,b0.w,b1v.x,b1v.y,b1v.z,b1v.w}; \
    _Pragma("unroll") \
    for(int ii=0;ii<4;ii++) \
      _Pragma("unroll") \
      for(int jj=0;jj<8;jj++) ACCVAR[ii][jj] = fmaf(av[ii], bv[jj], ACCVAR[ii][jj]); \
  }

template<int ACT>
__global__ __launch_bounds__(256)
void k_gemm(const float* __restrict__ A, int K,
            const float* __restrict__ W, const float* __restrict__ bias,
            float* __restrict__ out){
  __shared__ __align__(16) float As[KC][TM+4];
  __shared__ __align__(16) float Ws[KC][H];
  const int tid = threadIdx.x;
  const int tr = tid >> 4, tc = tid & 15;
  const int r0 = tr*4, c0 = tc*8;
  const int rowbase = blockIdx.x * TM;
  float acc[4][8];
#pragma unroll
  for (int i=0;i<4;i++)
#pragma unroll
    for (int j=0;j<8;j++) acc[i][j]=0.f;
  for (int kc=0; kc<K; kc+=KC){
    __syncthreads();
#pragma unroll
    for (int i=0;i<TM*KC/256;i++){
      int idx = tid + i*256; int k = idx & 63, r = idx >> 6;
      As[k][r] = A[(size_t)(rowbase + r)*K + kc + k];
    }
#pragma unroll
    for (int i=0;i<KC*H/256;i++){
      int idx = tid + i*256; int k = idx >> 7, c = idx & 127;
      Ws[k][c] = W[(kc + k)*H + c];
    }
    __syncthreads();
    GEMM_INNER(acc)
  }
#pragma unroll
  for (int i=0;i<4;i++){
    int row = rowbase + r0 + i;
    float4 o0, o1;
    o0.x = apply_act<ACT>(acc[i][0]+bias[c0+0]); o0.y = apply_act<ACT>(acc[i][1]+bias[c0+1]);
    o0.z = apply_act<ACT>(acc[i][2]+bias[c0+2]); o0.w = apply_act<ACT>(acc[i][3]+bias[c0+3]);
    o1.x = apply_act<ACT>(acc[i][4]+bias[c0+4]); o1.y = apply_act<ACT>(acc[i][5]+bias[c0+5]);
    o1.z = apply_act<ACT>(acc[i][6]+bias[c0+6]); o1.w = apply_act<ACT>(acc[i][7]+bias[c0+7]);
    *(float4*)&out[(size_t)row*H + c0]   = o0;
    *(float4*)&out[(size_t)row*H + c0+4] = o1;
  }
}

template<int ACT>
__global__ __launch_bounds__(256)
void k_gemm_cat2(const float* __restrict__ A0, const float* __restrict__ A1,
                 const float* __restrict__ W, const float* __restrict__ bias,
                 float* __restrict__ out){
  __shared__ __align__(16) float As[KC][TM+4];
  __shared__ __align__(16) float Ws[KC][H];
  const int tid = threadIdx.x;
  const int tr = tid >> 4, tc = tid & 15;
  const int r0 = tr*4, c0 = tc*8;
  const int rowbase = blockIdx.x * TM;
  float acc[4][8];
#pragma unroll
  for (int i=0;i<4;i++)
#pragma unroll
    for (int j=0;j<8;j++) acc[i][j]=0.f;
  for (int kc=0; kc<2*H; kc+=KC){
    const float* Ap = (kc >> 7) ? A1 : A0;
    const int kl = kc & 127;
    __syncthreads();
#pragma unroll
    for (int i=0;i<TM*KC/256;i++){
      int idx = tid + i*256; int k = idx & 63, r = idx >> 6;
      As[k][r] = Ap[(rowbase + r)*H + kl + k];
    }
#pragma unroll
    for (int i=0;i<KC*H/256;i++){
      int idx = tid + i*256; int k = idx >> 7, c = idx & 127;
      Ws[k][c] = W[(kc + k)*H + c];
    }
    __syncthreads();
    GEMM_INNER(acc)
  }
#pragma unroll
  for (int i=0;i<4;i++){
    int row = rowbase + r0 + i;
    float4 o0, o1;
    o0.x = apply_act<ACT>(acc[i][0]+bias[c0+0]); o0.y = apply_act<ACT>(acc[i][1]+bias[c0+1]);
    o0.z = apply_act<ACT>(acc[i][2]+bias[c0+2]); o0.w = apply_act<ACT>(acc[i][3]+bias[c0+3]);
    o1.x = apply_act<ACT>(acc[i][4]+bias[c0+4]); o1.y = apply_act<ACT>(acc[i][5]+bias[c0+5]);
    o1.z = apply_act<ACT>(acc[i][6]+bias[c0+6]); o1.w = apply_act<ACT>(acc[i][7]+bias[c0+7]);
    *(float4*)&out[row*H + c0]   = o0;
    *(float4*)&out[row*H + c0+4] = o1;
  }
}

template<int ADDSUM>
__global__ __launch_bounds__(256)
void k_upd2_ln(const float* __restrict__ hn, const float* __restrict__ W,
               const float* __restrict__ b2, const float* __restrict__ lng,
               const float* __restrict__ lnb, float* __restrict__ x,
               float* __restrict__ sumf, u16* __restrict__ xb){
  __shared__ __align__(16) float Ws[KC][H];
  __shared__ float As[16][H+1];
  const int tid = threadIdx.x;
  const int row = tid >> 4, cg = tid & 15, c0 = cg*8;
  const int rowbase = blockIdx.x * 16;
#pragma unroll
  for (int i=0;i<16*H/256;i++){
    int idx = tid + i*256; int r = idx >> 7, k = idx & 127;
    As[r][k] = hn[(rowbase + r)*H + k];
  }
  float acc[8] = {0,0,0,0,0,0,0,0};
  for (int kc=0; kc<H; kc+=KC){
#pragma unroll
    for (int i=0;i<KC*H/256;i++){
      int idx = tid + i*256; int k = idx >> 7, c = idx & 127;
      Ws[k][c] = W[(kc + k)*H + c];
    }
    __syncthreads();
#pragma unroll 4
    for (int k=0;k<KC;k++){
      float a = As[row][kc+k];
      const float4 w0 = *(const float4*)&Ws[k][c0];
      const float4 w1 = *(const float4*)&Ws[k][c0+4];
      acc[0]=fmaf(a,w0.x,acc[0]); acc[1]=fmaf(a,w0.y,acc[1]);
      acc[2]=fmaf(a,w0.z,acc[2]); acc[3]=fmaf(a,w0.w,acc[3]);
      acc[4]=fmaf(a,w1.x,acc[4]); acc[5]=fmaf(a,w1.y,acc[5]);
      acc[6]=fmaf(a,w1.z,acc[6]); acc[7]=fmaf(a,w1.w,acc[7]);
    }
    __syncthreads();
  }
  const int ro = (rowbase + row)*H;
  float y[8]; float s=0.f, ss=0.f;
#pragma unroll
  for (int j=0;j<8;j++){ y[j] = x[ro+c0+j] + acc[j] + b2[c0+j]; s += y[j]; ss += y[j]*y[j]; }
#pragma unroll
  for (int m=8;m>=1;m>>=1){ s += __shfl_xor(s,m,16); ss += __shfl_xor(ss,m,16); }
  float mean = s*(1.0f/H);
  float var  = ss*(1.0f/H) - mean*mean;
  float inv  = rsqrtf(var + 1e-5f);
  unsigned pk[4];
#pragma unroll
  for (int j=0;j<8;j++){
    float o = (y[j]-mean)*inv*lng[c0+j] + lnb[c0+j];
    x[ro+c0+j] = o;
    if (ADDSUM) sumf[ro+c0+j] += o;
    if (j & 1) pk[j>>1] |= ((unsigned)f2bf(o)) << 16;
    else       pk[j>>1]  = (unsigned)f2bf(o);
  }
  *(uint4*)&xb[ro+c0] = make_uint4(pk[0],pk[1],pk[2],pk[3]);
}

__global__ __launch_bounds__(256)
void k_gscore(const float* __restrict__ ae, const float* __restrict__ W1,
              const float* __restrict__ b1, const float* __restrict__ w2,
              const float* __restrict__ b2, float* __restrict__ g){
  __shared__ __align__(16) float Ws[KC][H];
  __shared__ float As[16][H+1];
  const int tid = threadIdx.x;
  const int row = tid >> 4, cg = tid & 15, c0 = cg*8;
  const int rowbase = blockIdx.x * 16;
#pragma unroll
  for (int i=0;i<16*H/256;i++){
    int idx = tid + i*256; int r = idx >> 7, k = idx & 127;
    As[r][k] = ae[(rowbase + r)*H + k];
  }
  float acc[8] = {0,0,0,0,0,0,0,0};
  for (int kc=0; kc<H; kc+=KC){
#pragma unroll
    for (int i=0;i<KC*H/256;i++){
      int idx = tid + i*256; int k = idx >> 7, c = idx & 127;
      Ws[k][c] = W1[(kc + k)*H + c];
    }
    __syncthreads();
#pragma unroll 4
    for (int k=0;k<KC;k++){
      float a = As[row][kc+k];
      const float4 w0 = *(const float4*)&Ws[k][c0];
      const float4 w1 = *(const float4*)&Ws[k][c0+4];
      acc[0]=fmaf(a,w0.x,acc[0]); acc[1]=fmaf(a,w0.y,acc[1]);
      acc[2]=fmaf(a,w0.z,acc[2]); acc[3]=fmaf(a,w0.w,acc[3]);
      acc[4]=fmaf(a,w1.x,acc[4]); acc[5]=fmaf(a,w1.y,acc[5]);
      acc[6]=fmaf(a,w1.z,acc[6]); acc[7]=fmaf(a,w1.w,acc[7]);
    }
    __syncthreads();
  }
  float p = 0.f;
#pragma unroll
  for (int j=0;j<8;j++) p = fmaf(tanhf(acc[j] + b1[c0+j]), w2[c0+j], p);
#pragma unroll
  for (int m=8;m>=1;m>>=1) p += __shfl_xor(p,m,16);
  if (cg == 0) g[rowbase + row] = p + b2[0];
}

__global__ void k_start(const int* __restrict__ batch, int* __restrict__ start){
  int b = threadIdx.x;
  if (b > NB) return;
  if (b == NB){ start[NB] = NN; return; }
  int lo = 0, hi = NN;
  while (lo < hi){ int mid = (lo+hi) >> 1; if (batch[mid] < b) lo = mid+1; else hi = mid; }
  start[b] = lo;
}

__global__ __launch_bounds__(256)
void k_pool(const int* __restrict__ start, const float* __restrict__ g,
            float* __restrict__ exb, const float* __restrict__ h,
            float* __restrict__ out){
  const int b = blockIdx.x;
  const int s = start[b], e = start[b+1];
  const int tid = threadIdx.x;
  __shared__ float red[4];
  __shared__ float s_gmax, s_den;
  __shared__ float part[2][H];

  float mx = -1e30f;
  for (int n = s + tid; n < e; n += 256) mx = fmaxf(mx, g[n]);
#pragma unroll
  for (int m=32;m>=1;m>>=1) mx = fmaxf(mx, __shfl_xor(mx, m, 64));
  if ((tid & 63) == 0) red[tid >> 6] = mx;
  __syncthreads();
  if (tid == 0){
    float v = fmaxf(fmaxf(red[0],red[1]), fmaxf(red[2],red[3]));
    s_gmax = (e > s) ? v : 0.0f;
  }
  __syncthreads();
  const float gmax = s_gmax;

  float sum = 0.f;
  for (int n = s + tid; n < e; n += 256){
    float ex = __expf(g[n] - gmax);
    exb[n] = ex;
    sum += ex;
  }
#pragma unroll
  for (int m=32;m>=1;m>>=1) sum += __shfl_xor(sum, m, 64);
  if ((tid & 63) == 0) red[tid >> 6] = sum;
  __syncthreads();
  if (tid == 0) s_den = red[0]+red[1]+red[2]+red[3];
  __syncthreads();
  const float den = s_den;

  const int col = tid & 127, rg = tid >> 7;
  float acc = 0.f;
  for (int n = s + rg; n < e; n += 2) acc = fmaf(exb[n], h[n*H + col], acc);
  part[rg][col] = acc;
  __syncthreads();
  if (tid < H){
    float v = part[0][tid] + part[1][tid];
    out[b*H + tid] = (den > 0.f) ? v/den : 0.0f;
  }
}

// ================================================================ host
extern "C" void kernel_launch(void* const* d_in, const int* in_sizes, int n_in,
                              void* d_out, int out_size, void* d_ws, size_t ws_size,
                              hipStream_t stream){
  const int*   Z      = (const int*)  d_in[0];
  const float* pos    = (const float*)d_in[1];
  const int*   batch  = (const int*)  d_in[2];
  const int*   ei     = (const int*)  d_in[3];
  const float* embed  = (const float*)d_in[4];
  const float* widths = (const float*)d_in[5];
  const float* ee_w1  = (const float*)d_in[6];
  const float* ee_b1  = (const float*)d_in[7];
  const float* ee_w2  = (const float*)d_in[8];
  const float* ee_b2  = (const float*)d_in[9];
  const float* msg_w1 = (const float*)d_in[10];
  const float* msg_b1 = (const float*)d_in[11];
  const float* msg_w2 = (const float*)d_in[12];
  const float* msg_b2 = (const float*)d_in[13];
  const float* gate_w = (const float*)d_in[14];
  const float* gate_b = (const float*)d_in[15];
  const float* upd_w1 = (const float*)d_in[16];
  const float* upd_b1 = (const float*)d_in[17];
  const float* upd_w2 = (const float*)d_in[18];
  const float* upd_b2 = (const float*)d_in[19];
  const float* ln_g   = (const float*)d_in[20];
  const float* ln_b   = (const float*)d_in[21];
  const float* gp_w1  = (const float*)d_in[22];
  const float* gp_b1  = (const float*)d_in[23];
  const float* gp_w2  = (const float*)d_in[24];
  const float* gp_b2  = (const float*)d_in[25];
  const float* pn_w   = (const float*)d_in[26];
  const float* pn_b   = (const float*)d_in[27];
  const float* ro_w1  = (const float*)d_in[28];
  const float* ro_b1  = (const float*)d_in[29];
  const float* ro_w2  = (const float*)d_in[30];
  const float* ro_b2  = (const float*)d_in[31];

  const int* srcv = ei;
  const int* dstv = ei + NE;

  // ---- workspace carve (64B-aligned blocks)
  char* p0 = (char*)d_ws;
  char* p = p0;
  auto carve = [&](size_t bytes)->char*{ char* q = p; p += (bytes + 63) & ~(size_t)63; return q; };
  float* x     = (float*)carve((size_t)NH*4);
  float* aggr  = (float*)carve((size_t)NH*4);
  float* hn    = (float*)carve((size_t)NH*4);
  float* gsc   = (float*)carve((size_t)NN*4);
  float* exb   = (float*)carve((size_t)NN*4);
  int*   startb  = (int*)carve((size_t)(NB+2)*4);
  int*   estart  = (int*)carve((size_t)(NN+1)*4);
  int*   ecursor = (int*)carve((size_t)NN*4);
  int*   src_s   = (int*)carve((size_t)NE*4);
  int*   dst_s   = (int*)carve((size_t)NE*4);
  u16*   xb      = (u16*)carve((size_t)NH*2);
  u16*   packw   = (u16*)carve((size_t)4*LT*2);
  size_t fixed   = (size_t)(p - p0);

  int NC = 1;
  while (NC < 256){
    size_t need = fixed + 2*(((size_t)(NE/NC)*H*2 + 63) & ~(size_t)63);
    if (need <= ws_size) break;
    NC <<= 1;
  }
  const int CH = NE / NC;
  u16* bufEE  = (u16*)carve((size_t)CH*H*2);
  u16* bufMSG = (u16*)carve((size_t)CH*H*2);

  float* out_af  = (float*)d_out;     // running sum of last-3 feats, then /3
  float* out_ae  = out_af + NH;
  float* out_gaf = out_ae + NH;

  // ---- once-per-call prep
  k_pack<<<dim3((LT+255)/256, 4), 256, 0, stream>>>(ee_w1, ee_w2, msg_w1, msg_w2, gate_w, packw);
  k_zero_i<<<(NN+255)/256, 256, 0, stream>>>(ecursor, NN);
  k_hist<<<NE/256, 256, 0, stream>>>(dstv, ecursor);
  k_scan<<<1, 1024, 0, stream>>>(ecursor, estart);
  k_scatter<<<NE/256, 256, 0, stream>>>(srcv, dstv, ecursor, src_s, dst_s);
  k_embed<<<NH/256, 256, 0, stream>>>(Z, embed, x, xb);
  k_zero<<<NH/256, 256, 0, stream>>>(out_af, NH);

  for (int l=0; l<4; l++){
    const u16* pw = packw + (size_t)l*LT;
    k_zero<<<NH/256, 256, 0, stream>>>(aggr, NH);
    for (int c=0; c<NC; c++){
      const int eo = c*CH;
      k_ee<<<CH/TM, 256, 0, stream>>>(src_s+eo, dst_s+eo, pos, widths,
                                      pw, ee_b1 + l*H, pw + 8192, ee_b2 + l*H, bufEE);
      k_msg1<<<CH/TM, 256, 0, stream>>>(xb, bufEE, src_s+eo, dst_s+eo,
                                        pw + 24576, msg_b1 + l*H, bufMSG);
      k_msg2<<<CH/TM, 256, 0, stream>>>(bufMSG, bufEE,
                                        pw + 73728, msg_b2 + l*H,
                                        pw + 90112, gate_b + l*H);
      k_aggr<<<NN/2, 256, 0, stream>>>(estart, bufMSG, eo, CH, aggr);
    }
    k_gemm_cat2<1><<<NN/TM, 256, 0, stream>>>(aggr, x,
                                              upd_w1 + l*2*H*H, upd_b1 + l*H, hn);
    if (l == 0)
      k_upd2_ln<0><<<NN/16, 256, 0, stream>>>(hn, upd_w2 + l*H*H, upd_b2 + l*H,
                                              ln_g + l*H, ln_b + l*H, x, out_af, xb);
    else
      k_upd2_ln<1><<<NN/16, 256, 0, stream>>>(hn, upd_w2 + l*H*H, upd_b2 + l*H,
                                              ln_g + l*H, ln_b + l*H, x, out_af, xb);
  }

  k_af<<<NH/256, 256, 0, stream>>>(out_af, out_af);
  k_gemm<1><<<NN/TM, 256, 0, stream>>>(out_af, H, ro_w1, ro_b1, hn);
  k_gemm<0><<<NN/TM, 256, 0, stream>>>(hn, H, ro_w2, ro_b2, out_ae);
  k_gscore<<<NN/16, 256, 0, stream>>>(out_ae, gp_w1, gp_b1, gp_w2, gp_b2, gsc);
  k_gemm<1><<<NN/TM, 256, 0, stream>>>(out_ae, H, pn_w, pn_b, hn);
  k_start<<<1, 64, 0, stream>>>(batch, startb);
  k_pool<<<NB, 256, 0, stream>>>(startb, gsc, exb, hn, out_gaf);
}

// Round 4
// 1433.340 us; speedup vs baseline: 5.5234x; 1.2253x over previous
//
#include <hip/hip_runtime.h>

#define NN   16384
#define NE   262144
#define NB   32
#define H    128
#define NH   (NN*H)
#define RBF  50
#define TM   64
#define KC   64
#define KP   72     // A/W staging pitch (u16): 144 B, 16B-aligned rows, non-pow2 banks
#define HBP  136    // Eb/Sb pitch (u16): 272 B, 16B-aligned rows
#define LT   106496 // packed weights per layer (u16 elems)

typedef unsigned short u16;
typedef short bf16x8 __attribute__((ext_vector_type(8)));
typedef float f32x4 __attribute__((ext_vector_type(4)));

__device__ __forceinline__ float sigmoidf_(float v){ return 1.0f/(1.0f + __expf(-v)); }
__device__ __forceinline__ float siluf_(float v){ return v * sigmoidf_(v); }
__device__ __forceinline__ u16 f2bf(float f){
  unsigned u = __float_as_uint(f);
  return (u16)((u + 0x7FFFu + ((u>>16)&1u)) >> 16);
}
__device__ __forceinline__ float bf2f(u16 v){ return __uint_as_float(((unsigned)v)<<16); }

template<int ACT>
__device__ __forceinline__ float apply_act(float v){ return (ACT==1) ? siluf_(v) : v; }

// ---- MFMA helpers (use: tid, wrow, l15, q8 from scope) ----
#define STAGE_WT(GSRC, KPAD, K0) \
  _Pragma("unroll") \
  for (int i_=0;i_<4;i_++){ \
    int o_ = tid + i_*256; \
    int c_ = o_ >> 3, ko_ = (o_ & 7)*8; \
    *(uint4*)&Wt[c_][ko_] = *(const uint4*)((GSRC) + (size_t)c_*(KPAD) + (K0) + ko_); \
  }

#define STAGE_AB(ROWPTR) \
  _Pragma("unroll") \
  for (int i_=0;i_<2;i_++){ \
    int o_ = tid*2 + i_; \
    int r_ = o_ >> 3, ko_ = (o_ & 7)*8; \
    const u16* rp_ = (ROWPTR); \
    *(uint4*)&Ab[r_][ko_] = *(const uint4*)(rp_ + ko_); \
  }

#define MFMA_TILES(ABUF, KOFF, ACC) \
  _Pragma("unroll") \
  for (int ks_=0; ks_<KC; ks_+=32){ \
    bf16x8 af_ = *(const bf16x8*)&ABUF[wrow + l15][(KOFF) + ks_ + q8]; \
    _Pragma("unroll") \
    for (int t_=0;t_<8;t_++){ \
      bf16x8 bf_ = *(const bf16x8*)&Wt[t_*16 + l15][ks_ + q8]; \
      ACC[t_] = __builtin_amdgcn_mfma_f32_16x16x32_bf16(af_, bf_, ACC[t_], 0, 0, 0); \
    } \
  }

// ---------------------------------------------------------------- utility
__global__ void k_zero(float* __restrict__ p, int n){
  int i = blockIdx.x*256 + threadIdx.x; if (i < n) p[i] = 0.f;
}
__global__ void k_zero_i(int* __restrict__ p, int n){
  int i = blockIdx.x*256 + threadIdx.x; if (i < n) p[i] = 0;
}
__global__ void k_embed(const int* __restrict__ z, const float* __restrict__ emb,
                        float* __restrict__ x, u16* __restrict__ xb){
  int i = blockIdx.x*256 + threadIdx.x;
  int n = i >> 7, h = i & 127;
  float v = emb[z[n]*H + h];
  x[i] = v; xb[i] = f2bf(v);
}
__global__ void k_af(const float* __restrict__ s, float* __restrict__ o){
  int i = blockIdx.x*256 + threadIdx.x;
  o[i] = s[i]*(1.0f/3.0f);
}

// ---------------------------------------------------------------- weight pack (f32 [K][128] -> bf16 [128][Kpad])
__global__ void k_pack(const float* __restrict__ ee_w1, const float* __restrict__ ee_w2,
                       const float* __restrict__ msg_w1, const float* __restrict__ msg_w2,
                       const float* __restrict__ gate_w, u16* __restrict__ out){
  int idx = blockIdx.x*256 + threadIdx.x;
  int l = blockIdx.y;
  if (idx >= LT) return;
  u16* o = out + (size_t)l*LT;
  float v; int c, k;
  if (idx < 8192){            c = idx>>6;  k = idx&63;
    v = (k<RBF) ? ee_w1[(size_t)l*RBF*H + k*H + c] : 0.f; }
  else if (idx < 24576){ int j=idx-8192;  c=j>>7; k=j&127;
    v = ee_w2[(size_t)l*H*H + k*H + c]; }
  else if (idx < 73728){ int j=idx-24576; c=j/384; k=j%384;
    v = msg_w1[(size_t)l*3*H*H + k*H + c]; }
  else if (idx < 90112){ int j=idx-73728; c=j>>7; k=j&127;
    v = msg_w2[(size_t)l*H*H + k*H + c]; }
  else {                 int j=idx-90112; c=j>>7; k=j&127;
    v = gate_w[(size_t)l*H*H + k*H + c]; }
  o[idx] = f2bf(v);
}

// ---------------------------------------------------------------- edge sort by dst (counting sort)
__global__ void k_hist(const int* __restrict__ dstv, int* __restrict__ cnt){
  int e = blockIdx.x*256 + threadIdx.x;
  if (e < NE) atomicAdd(&cnt[dstv[e]], 1);
}
__global__ __launch_bounds__(1024)
void k_scan(int* __restrict__ cnt, int* __restrict__ start){
  __shared__ int ps[1024];
  int tid = threadIdx.x;
  int base = tid*16;
  int loc[16]; int s = 0;
#pragma unroll
  for (int i=0;i<16;i++){ loc[i] = s; s += cnt[base+i]; }
  ps[tid] = s; __syncthreads();
  for (int off=1; off<1024; off<<=1){
    int v = (tid>=off) ? ps[tid-off] : 0;
    __syncthreads();
    ps[tid] += v;
    __syncthreads();
  }
  int pre = (tid>0) ? ps[tid-1] : 0;
#pragma unroll
  for (int i=0;i<16;i++){ int v = pre + loc[i]; start[base+i] = v; cnt[base+i] = v; }
  if (tid == 0) start[NN] = NE;
}
__global__ void k_scatter(const int* __restrict__ srcv, const int* __restrict__ dstv,
                          int* __restrict__ cursor, int* __restrict__ src_s,
                          int* __restrict__ dst_s){
  int e = blockIdx.x*256 + threadIdx.x;
  if (e >= NE) return;
  int d = dstv[e];
  int p = atomicAdd(&cursor[d], 1);
  src_s[p] = srcv[e]; dst_s[p] = d;
}

// ---------------------------------------------------------------- FUSED edge pipeline:
// RBF -> ee1(silu) -> ee2 -> msg1(concat,silu) -> msg2 * sigmoid(gate) -> segmented reduce -> aggr
__global__ __launch_bounds__(256)
void k_edge(const int* __restrict__ src_s, const int* __restrict__ dst_s,
            const float* __restrict__ pos, const float* __restrict__ widths,
            const u16* __restrict__ xb, const u16* __restrict__ pw,
            const float* __restrict__ b_ee1, const float* __restrict__ b_ee2,
            const float* __restrict__ b_m1, const float* __restrict__ b_m2,
            const float* __restrict__ b_g,
            float* __restrict__ aggr){
  __shared__ u16 Ab[TM][KP];     // A staging (RBF / x gathers)
  __shared__ u16 Wt[H][KP];      // weight chunk staging
  __shared__ u16 Eb[TM][HBP];    // ee result
  __shared__ u16 Sb[TM][HBP];    // hidden / msg / gated (rotating)
  __shared__ int gdst[TM], gsrc[TM];
  __shared__ float dls[TM], cls[TM], gls[KC];
  __shared__ float bbA[H], bbB[H];   // rotating bias slots

  const int tid = threadIdx.x;
  const int wave = tid>>6, l = tid&63, l15 = l&15, quad = l>>4;
  const int wrow = wave*16, q8 = quad*8;
  const int rowbase = blockIdx.x*TM;

  const u16* w_ee1 = pw;
  const u16* w_ee2 = pw + 8192;
  const u16* w_m1  = pw + 24576;
  const u16* w_m2  = pw + 73728;
  const u16* w_g   = pw + 90112;

  // ---- S0: meta + RBF params + ee biases + ee1 weights
  STAGE_WT(w_ee1, 64, 0)
  if (tid < TM){
    int e = rowbase + tid;
    int s = src_s[e], d = dst_s[e];
    gsrc[tid] = s; gdst[tid] = d;
    float dx = pos[3*d]-pos[3*s], dy = pos[3*d+1]-pos[3*s+1], dz = pos[3*d+2]-pos[3*s+2];
    float dist = sqrtf(dx*dx + dy*dy + dz*dz);
    dls[tid] = dist;
    cls[tid] = (dist < 5.0f) ? 0.5f*(__cosf(0.62831853f*dist) + 1.0f) : 0.0f;
  } else if (tid < TM+KC){
    int k = tid - TM;
    float w = (k < RBF) ? widths[k] : 1.0f;
    gls[k] = 1.0f/(2.0f*w*w);
  } else {
    int t = tid - 128;
    bbA[t] = b_ee1[t]; bbB[t] = b_ee2[t];
  }
  __syncthreads();                             // A
  { // RBF -> Ab
    int r = tid>>2, kb = (tid&3)*16;
    float dr = dls[r], cr = cls[r];
#pragma unroll
    for (int kk=0; kk<16; kk+=2){
      int k0 = kb+kk, k1 = kb+kk+1;
      float t0 = dr - 0.10204082f*(float)k0;
      float t1 = dr - 0.10204082f*(float)k1;
      float v0 = (k0 < RBF) ? __expf(-gls[k0]*t0*t0)*cr : 0.f;
      float v1 = (k1 < RBF) ? __expf(-gls[k1]*t1*t1)*cr : 0.f;
      *(unsigned*)&Ab[r][k0] = (unsigned)f2bf(v0) | ((unsigned)f2bf(v1)<<16);
    }
  }
  __syncthreads();                             // B

  f32x4 acc[8];
#pragma unroll
  for (int t=0;t<8;t++) acc[t] = (f32x4)(0.f);
  MFMA_TILES(Ab, 0, acc)                       // ee1 (K=64)
#pragma unroll
  for (int t=0;t<8;t++){                       // hidden silu -> Sb
    int col = t*16 + l15; float b = bbA[col];
#pragma unroll
    for (int r=0;r<4;r++) Sb[wrow + quad*4 + r][col] = f2bf(siluf_(acc[t][r] + b));
  }
  __syncthreads();                             // C

#pragma unroll
  for (int t=0;t<8;t++) acc[t] = (f32x4)(0.f);
  for (int kc=0; kc<H; kc+=KC){                // ee2 (K=128)
    STAGE_WT(w_ee2, 128, kc)
    __syncthreads();                           // D
    MFMA_TILES(Sb, kc, acc)
    __syncthreads();                           // E
  }
#pragma unroll
  for (int t=0;t<8;t++){                       // ee -> Eb
    int col = t*16 + l15; float b = bbB[col];
#pragma unroll
    for (int r=0;r<4;r++) Eb[wrow + quad*4 + r][col] = f2bf(acc[t][r] + b);
  }

#pragma unroll
  for (int t=0;t<8;t++) acc[t] = (f32x4)(0.f);
  for (int kc6=0; kc6<6; kc6++){               // msg1 (K=384)
    if (kc6 < 2)      { const int kl = kc6*64;     STAGE_AB(xb + (size_t)gdst[r_]*H + kl) }
    else if (kc6 < 4) { const int kl = (kc6-2)*64; STAGE_AB(xb + (size_t)gsrc[r_]*H + kl) }
    STAGE_WT(w_m1, 384, kc6*64)
    if (kc6 == 0 && tid < H) bbA[tid] = b_m1[tid];
    __syncthreads();                           // F
    if (kc6 < 4) { MFMA_TILES(Ab, 0, acc) }
    else         { MFMA_TILES(Eb, (kc6-4)*64, acc) }
    __syncthreads();                           // G
  }
#pragma unroll
  for (int t=0;t<8;t++){                       // msg hidden silu -> Sb
    int col = t*16 + l15; float b = bbA[col];
#pragma unroll
    for (int r=0;r<4;r++) Sb[wrow + quad*4 + r][col] = f2bf(siluf_(acc[t][r] + b));
  }
  __syncthreads();                             // H

  f32x4 accG[8];
#pragma unroll
  for (int t=0;t<8;t++){ acc[t] = (f32x4)(0.f); accG[t] = (f32x4)(0.f); }
  for (int kc=0; kc<H; kc+=KC){                // msg2 (K=128)
    STAGE_WT(w_m2, 128, kc)
    if (kc == 0){ if (tid < H) bbB[tid] = b_m2[tid]; else bbA[tid-H] = b_g[tid-H]; }
    __syncthreads();                           // I
    MFMA_TILES(Sb, kc, acc)
    __syncthreads();                           // J
  }
  for (int kc=0; kc<H; kc+=KC){                // gate (K=128)
    STAGE_WT(w_g, 128, kc)
    __syncthreads();                           // K
    MFMA_TILES(Eb, kc, accG)
    __syncthreads();                           // L
  }
#pragma unroll
  for (int t=0;t<8;t++){                       // gated message -> Sb
    int col = t*16 + l15;
    float bm = bbB[col], bg = bbA[col];
#pragma unroll
    for (int r=0;r<4;r++){
      float m  = acc[t][r] + bm;
      float gt = sigmoidf_(accG[t][r] + bg);
      Sb[wrow + quad*4 + r][col] = f2bf(m*gt);
    }
  }
  __syncthreads();                             // M

  // segmented reduce over dst-sorted rows; atomic per run boundary
  { int col = tid & 127, half = tid >> 7;
    int rbeg = half*32, rend = rbeg + 32;
    float a = 0.f; int cur = gdst[rbeg];
    for (int r=rbeg; r<rend; r++){
      int d = gdst[r];
      if (d != cur){ atomicAdd(&aggr[(size_t)cur*H + col], a); a = 0.f; cur = d; }
      a += bf2f(Sb[r][col]);
    }
    atomicAdd(&aggr[(size_t)cur*H + col], a);
  }
}

// ---------------------------------------------------------------- f32 node-side kernels
#define GEMM_INNER(ACCVAR) \
  _Pragma("unroll 4") \
  for (int k=0;k<KC;k++){ \
    const float4 a  = *(const float4*)&As[k][r0]; \
    const float4 b0 = *(const float4*)&Ws[k][c0]; \
    const float4 b1v = *(const float4*)&Ws[k][c0+4]; \
    float av[4]={a.x,a.y,a.z,a.w}; \
    float bv[8]={b0.x,b0.y,b0.z,b0.w,b1v.x,b1v.y,b1v.z,b1v.w}; \
    _Pragma("unroll") \
    for(int ii=0;ii<4;ii++) \
      _Pragma("unroll") \
      for(int jj=0;jj<8;jj++) ACCVAR[ii][jj] = fmaf(av[ii], bv[jj], ACCVAR[ii][jj]); \
  }

template<int ACT>
__global__ __launch_bounds__(256)
void k_gemm(const float* __restrict__ A, int K,
            const float* __restrict__ W, const float* __restrict__ bias,
            float* __restrict__ out){
  __shared__ __align__(16) float As[KC][TM+4];
  __shared__ __align__(16) float Ws[KC][H];
  const int tid = threadIdx.x;
  const int tr = tid >> 4, tc = tid & 15;
  const int r0 = tr*4, c0 = tc*8;
  const int rowbase = blockIdx.x * TM;
  float acc[4][8];
#pragma unroll
  for (int i=0;i<4;i++)
#pragma unroll
    for (int j=0;j<8;j++) acc[i][j]=0.f;
  for (int kc=0; kc<K; kc+=KC){
    __syncthreads();
#pragma unroll
    for (int i=0;i<TM*KC/256;i++){
      int idx = tid + i*256; int k = idx & 63, r = idx >> 6;
      As[k][r] = A[(size_t)(rowbase + r)*K + kc + k];
    }
#pragma unroll
    for (int i=0;i<KC*H/256;i++){
      int idx = tid + i*256; int k = idx >> 7, c = idx & 127;
      Ws[k][c] = W[(kc + k)*H + c];
    }
    __syncthreads();
    GEMM_INNER(acc)
  }
#pragma unroll
  for (int i=0;i<4;i++){
    int row = rowbase + r0 + i;
    float4 o0, o1;
    o0.x = apply_act<ACT>(acc[i][0]+bias[c0+0]); o0.y = apply_act<ACT>(acc[i][1]+bias[c0+1]);
    o0.z = apply_act<ACT>(acc[i][2]+bias[c0+2]); o0.w = apply_act<ACT>(acc[i][3]+bias[c0+3]);
    o1.x = apply_act<ACT>(acc[i][4]+bias[c0+4]); o1.y = apply_act<ACT>(acc[i][5]+bias[c0+5]);
    o1.z = apply_act<ACT>(acc[i][6]+bias[c0+6]); o1.w = apply_act<ACT>(acc[i][7]+bias[c0+7]);
    *(float4*)&out[(size_t)row*H + c0]   = o0;
    *(float4*)&out[(size_t)row*H + c0+4] = o1;
  }
}

template<int ACT>
__global__ __launch_bounds__(256)
void k_gemm_cat2(const float* __restrict__ A0, const float* __restrict__ A1,
                 const float* __restrict__ W, const float* __restrict__ bias,
                 float* __restrict__ out){
  __shared__ __align__(16) float As[KC][TM+4];
  __shared__ __align__(16) float Ws[KC][H];
  const int tid = threadIdx.x;
  const int tr = tid >> 4, tc = tid & 15;
  const int r0 = tr*4, c0 = tc*8;
  const int rowbase = blockIdx.x * TM;
  float acc[4][8];
#pragma unroll
  for (int i=0;i<4;i++)
#pragma unroll
    for (int j=0;j<8;j++) acc[i][j]=0.f;
  for (int kc=0; kc<2*H; kc+=KC){
    const float* Ap = (kc >> 7) ? A1 : A0;
    const int kl = kc & 127;
    __syncthreads();
#pragma unroll
    for (int i=0;i<TM*KC/256;i++){
      int idx = tid + i*256; int k = idx & 63, r = idx >> 6;
      As[k][r] = Ap[(rowbase + r)*H + kl + k];
    }
#pragma unroll
    for (int i=0;i<KC*H/256;i++){
      int idx = tid + i*256; int k = idx >> 7, c = idx & 127;
      Ws[k][c] = W[(kc + k)*H + c];
    }
    __syncthreads();
    GEMM_INNER(acc)
  }
#pragma unroll
  for (int i=0;i<4;i++){
    int row = rowbase + r0 + i;
    float4 o0, o1;
    o0.x = apply_act<ACT>(acc[i][0]+bias[c0+0]); o0.y = apply_act<ACT>(acc[i][1]+bias[c0+1]);
    o0.z = apply_act<ACT>(acc[i][2]+bias[c0+2]); o0.w = apply_act<ACT>(acc[i][3]+bias[c0+3]);
    o1.x = apply_act<ACT>(acc[i][4]+bias[c0+4]); o1.y = apply_act<ACT>(acc[i][5]+bias[c0+5]);
    o1.z = apply_act<ACT>(acc[i][6]+bias[c0+6]); o1.w = apply_act<ACT>(acc[i][7]+bias[c0+7]);
    *(float4*)&out[row*H + c0]   = o0;
    *(float4*)&out[row*H + c0+4] = o1;
  }
}

template<int ADDSUM>
__global__ __launch_bounds__(256)
void k_upd2_ln(const float* __restrict__ hn, const float* __restrict__ W,
               const float* __restrict__ b2, const float* __restrict__ lng,
               const float* __restrict__ lnb, float* __restrict__ x,
               float* __restrict__ sumf, u16* __restrict__ xb){
  __shared__ __align__(16) float Ws[KC][H];
  __shared__ float As[16][H+1];
  const int tid = threadIdx.x;
  const int row = tid >> 4, cg = tid & 15, c0 = cg*8;
  const int rowbase = blockIdx.x * 16;
#pragma unroll
  for (int i=0;i<16*H/256;i++){
    int idx = tid + i*256; int r = idx >> 7, k = idx & 127;
    As[r][k] = hn[(rowbase + r)*H + k];
  }
  float acc[8] = {0,0,0,0,0,0,0,0};
  for (int kc=0; kc<H; kc+=KC){
#pragma unroll
    for (int i=0;i<KC*H/256;i++){
      int idx = tid + i*256; int k = idx >> 7, c = idx & 127;
      Ws[k][c] = W[(kc + k)*H + c];
    }
    __syncthreads();
#pragma unroll 4
    for (int k=0;k<KC;k++){
      float a = As[row][kc+k];
      const float4 w0 = *(const float4*)&Ws[k][c0];
      const float4 w1 = *(const float4*)&Ws[k][c0+4];
      acc[0]=fmaf(a,w0.x,acc[0]); acc[1]=fmaf(a,w0.y,acc[1]);
      acc[2]=fmaf(a,w0.z,acc[2]); acc[3]=fmaf(a,w0.w,acc[3]);
      acc[4]=fmaf(a,w1.x,acc[4]); acc[5]=fmaf(a,w1.y,acc[5]);
      acc[6]=fmaf(a,w1.z,acc[6]); acc[7]=fmaf(a,w1.w,acc[7]);
    }
    __syncthreads();
  }
  const int ro = (rowbase + row)*H;
  float y[8]; float s=0.f, ss=0.f;
#pragma unroll
  for (int j=0;j<8;j++){ y[j] = x[ro+c0+j] + acc[j] + b2[c0+j]; s += y[j]; ss += y[j]*y[j]; }
#pragma unroll
  for (int m=8;m>=1;m>>=1){ s += __shfl_xor(s,m,16); ss += __shfl_xor(ss,m,16); }
  float mean = s*(1.0f/H);
  float var  = ss*(1.0f/H) - mean*mean;
  float inv  = rsqrtf(var + 1e-5f);
  unsigned pk[4];
#pragma unroll
  for (int j=0;j<8;j++){
    float o = (y[j]-mean)*inv*lng[c0+j] + lnb[c0+j];
    x[ro+c0+j] = o;
    if (ADDSUM) sumf[ro+c0+j] += o;
    if (j & 1) pk[j>>1] |= ((unsigned)f2bf(o)) << 16;
    else       pk[j>>1]  = (unsigned)f2bf(o);
  }
  *(uint4*)&xb[ro+c0] = make_uint4(pk[0],pk[1],pk[2],pk[3]);
}

__global__ __launch_bounds__(256)
void k_gscore(const float* __restrict__ ae, const float* __restrict__ W1,
              const float* __restrict__ b1, const float* __restrict__ w2,
              const float* __restrict__ b2, float* __restrict__ g){
  __shared__ __align__(16) float Ws[KC][H];
  __shared__ float As[16][H+1];
  const int tid = threadIdx.x;
  const int row = tid >> 4, cg = tid & 15, c0 = cg*8;
  const int rowbase = blockIdx.x * 16;
#pragma unroll
  for (int i=0;i<16*H/256;i++){
    int idx = tid + i*256; int r = idx >> 7, k = idx & 127;
    As[r][k] = ae[(rowbase + r)*H + k];
  }
  float acc[8] = {0,0,0,0,0,0,0,0};
  for (int kc=0; kc<H; kc+=KC){
#pragma unroll
    for (int i=0;i<KC*H/256;i++){
      int idx = tid + i*256; int k = idx >> 7, c = idx & 127;
      Ws[k][c] = W1[(kc + k)*H + c];
    }
    __syncthreads();
#pragma unroll 4
    for (int k=0;k<KC;k++){
      float a = As[row][kc+k];
      const float4 w0 = *(const float4*)&Ws[k][c0];
      const float4 w1 = *(const float4*)&Ws[k][c0+4];
      acc[0]=fmaf(a,w0.x,acc[0]); acc[1]=fmaf(a,w0.y,acc[1]);
      acc[2]=fmaf(a,w0.z,acc[2]); acc[3]=fmaf(a,w0.w,acc[3]);
      acc[4]=fmaf(a,w1.x,acc[4]); acc[5]=fmaf(a,w1.y,acc[5]);
      acc[6]=fmaf(a,w1.z,acc[6]); acc[7]=fmaf(a,w1.w,acc[7]);
    }
    __syncthreads();
  }
  float p = 0.f;
#pragma unroll
  for (int j=0;j<8;j++) p = fmaf(tanhf(acc[j] + b1[c0+j]), w2[c0+j], p);
#pragma unroll
  for (int m=8;m>=1;m>>=1) p += __shfl_xor(p,m,16);
  if (cg == 0) g[rowbase + row] = p + b2[0];
}

__global__ void k_start(const int* __restrict__ batch, int* __restrict__ start){
  int b = threadIdx.x;
  if (b > NB) return;
  if (b == NB){ start[NB] = NN; return; }
  int lo = 0, hi = NN;
  while (lo < hi){ int mid = (lo+hi) >> 1; if (batch[mid] < b) lo = mid+1; else hi = mid; }
  start[b] = lo;
}

__global__ __launch_bounds__(256)
void k_pool(const int* __restrict__ start, const float* __restrict__ g,
            float* __restrict__ exb, const float* __restrict__ h,
            float* __restrict__ out){
  const int b = blockIdx.x;
  const int s = start[b], e = start[b+1];
  const int tid = threadIdx.x;
  __shared__ float red[4];
  __shared__ float s_gmax, s_den;
  __shared__ float part[2][H];

  float mx = -1e30f;
  for (int n = s + tid; n < e; n += 256) mx = fmaxf(mx, g[n]);
#pragma unroll
  for (int m=32;m>=1;m>>=1) mx = fmaxf(mx, __shfl_xor(mx, m, 64));
  if ((tid & 63) == 0) red[tid >> 6] = mx;
  __syncthreads();
  if (tid == 0){
    float v = fmaxf(fmaxf(red[0],red[1]), fmaxf(red[2],red[3]));
    s_gmax = (e > s) ? v : 0.0f;
  }
  __syncthreads();
  const float gmax = s_gmax;

  float sum = 0.f;
  for (int n = s + tid; n < e; n += 256){
    float ex = __expf(g[n] - gmax);
    exb[n] = ex;
    sum += ex;
  }
#pragma unroll
  for (int m=32;m>=1;m>>=1) sum += __shfl_xor(sum, m, 64);
  if ((tid & 63) == 0) red[tid >> 6] = sum;
  __syncthreads();
  if (tid == 0) s_den = red[0]+red[1]+red[2]+red[3];
  __syncthreads();
  const float den = s_den;

  const int col = tid & 127, rg = tid >> 7;
  float acc = 0.f;
  for (int n = s + rg; n < e; n += 2) acc = fmaf(exb[n], h[n*H + col], acc);
  part[rg][col] = acc;
  __syncthreads();
  if (tid < H){
    float v = part[0][tid] + part[1][tid];
    out[b*H + tid] = (den > 0.f) ? v/den : 0.0f;
  }
}

// ================================================================ host
extern "C" void kernel_launch(void* const* d_in, const int* in_sizes, int n_in,
                              void* d_out, int out_size, void* d_ws, size_t ws_size,
                              hipStream_t stream){
  const int*   Z      = (const int*)  d_in[0];
  const float* pos    = (const float*)d_in[1];
  const int*   batch  = (const int*)  d_in[2];
  const int*   ei     = (const int*)  d_in[3];
  const float* embed  = (const float*)d_in[4];
  const float* widths = (const float*)d_in[5];
  const float* ee_w1  = (const float*)d_in[6];
  const float* ee_b1  = (const float*)d_in[7];
  const float* ee_w2  = (const float*)d_in[8];
  const float* ee_b2  = (const float*)d_in[9];
  const float* msg_w1 = (const float*)d_in[10];
  const float* msg_b1 = (const float*)d_in[11];
  const float* msg_w2 = (const float*)d_in[12];
  const float* msg_b2 = (const float*)d_in[13];
  const float* gate_w = (const float*)d_in[14];
  const float* gate_b = (const float*)d_in[15];
  const float* upd_w1 = (const float*)d_in[16];
  const float* upd_b1 = (const float*)d_in[17];
  const float* upd_w2 = (const float*)d_in[18];
  const float* upd_b2 = (const float*)d_in[19];
  const float* ln_g   = (const float*)d_in[20];
  const float* ln_b   = (const float*)d_in[21];
  const float* gp_w1  = (const float*)d_in[22];
  const float* gp_b1  = (const float*)d_in[23];
  const float* gp_w2  = (const float*)d_in[24];
  const float* gp_b2  = (const float*)d_in[25];
  const float* pn_w   = (const float*)d_in[26];
  const float* pn_b   = (const float*)d_in[27];
  const float* ro_w1  = (const float*)d_in[28];
  const float* ro_b1  = (const float*)d_in[29];
  const float* ro_w2  = (const float*)d_in[30];
  const float* ro_b2  = (const float*)d_in[31];

  const int* srcv = ei;
  const int* dstv = ei + NE;

  // ---- workspace carve (64B-aligned)
  char* p0 = (char*)d_ws;
  char* p = p0;
  auto carve = [&](size_t bytes)->char*{ char* q = p; p += (bytes + 63) & ~(size_t)63; return q; };
  float* x     = (float*)carve((size_t)NH*4);
  float* aggr  = (float*)carve((size_t)NH*4);
  float* hn    = (float*)carve((size_t)NH*4);
  float* gsc   = (float*)carve((size_t)NN*4);
  float* exb   = (float*)carve((size_t)NN*4);
  int*   startb  = (int*)carve((size_t)(NB+2)*4);
  int*   estart  = (int*)carve((size_t)(NN+1)*4);
  int*   ecursor = (int*)carve((size_t)NN*4);
  int*   src_s   = (int*)carve((size_t)NE*4);
  int*   dst_s   = (int*)carve((size_t)NE*4);
  u16*   xb      = (u16*)carve((size_t)NH*2);
  u16*   packw   = (u16*)carve((size_t)4*LT*2);

  float* out_af  = (float*)d_out;     // running sum of last-3 feats, then /3
  float* out_ae  = out_af + NH;
  float* out_gaf = out_ae + NH;

  // ---- once-per-call prep
  k_pack<<<dim3((LT+255)/256, 4), 256, 0, stream>>>(ee_w1, ee_w2, msg_w1, msg_w2, gate_w, packw);
  k_zero_i<<<(NN+255)/256, 256, 0, stream>>>(ecursor, NN);
  k_hist<<<NE/256, 256, 0, stream>>>(dstv, ecursor);
  k_scan<<<1, 1024, 0, stream>>>(ecursor, estart);
  k_scatter<<<NE/256, 256, 0, stream>>>(srcv, dstv, ecursor, src_s, dst_s);
  k_embed<<<NH/256, 256, 0, stream>>>(Z, embed, x, xb);
  k_zero<<<NH/256, 256, 0, stream>>>(out_af, NH);

  for (int l=0; l<4; l++){
    const u16* pw = packw + (size_t)l*LT;
    k_zero<<<NH/256, 256, 0, stream>>>(aggr, NH);
    k_edge<<<NE/TM, 256, 0, stream>>>(src_s, dst_s, pos, widths, xb, pw,
                                      ee_b1 + l*H, ee_b2 + l*H, msg_b1 + l*H,
                                      msg_b2 + l*H, gate_b + l*H, aggr);
    k_gemm_cat2<1><<<NN/TM, 256, 0, stream>>>(aggr, x,
                                              upd_w1 + l*2*H*H, upd_b1 + l*H, hn);
    if (l == 0)
      k_upd2_ln<0><<<NN/16, 256, 0, stream>>>(hn, upd_w2 + l*H*H, upd_b2 + l*H,
                                              ln_g + l*H, ln_b + l*H, x, out_af, xb);
    else
      k_upd2_ln<1><<<NN/16, 256, 0, stream>>>(hn, upd_w2 + l*H*H, upd_b2 + l*H,
                                              ln_g + l*H, ln_b + l*H, x, out_af, xb);
  }

  k_af<<<NH/256, 256, 0, stream>>>(out_af, out_af);
  k_gemm<1><<<NN/TM, 256, 0, stream>>>(out_af, H, ro_w1, ro_b1, hn);
  k_gemm<0><<<NN/TM, 256, 0, stream>>>(hn, H, ro_w2, ro_b2, out_ae);
  k_gscore<<<NN/16, 256, 0, stream>>>(out_ae, gp_w1, gp_b1, gp_w2, gp_b2, gsc);
  k_gemm<1><<<NN/TM, 256, 0, stream>>>(out_ae, H, pn_w, pn_b, hn);
  k_start<<<1, 64, 0, stream>>>(batch, startb);
  k_pool<<<NB, 256, 0, stream>>>(startb, gsc, exb, hn, out_gaf);
}

// Round 6
// 1053.263 us; speedup vs baseline: 7.5166x; 1.3609x over previous
//
#include <hip/hip_runtime.h>

#define NN   16384
#define NE   262144
#define NB   32
#define H    128
#define NH   (NN*H)
#define RBF  50
#define TM   64
#define KC   64
#define KP   72     // A/W staging pitch (u16): 144 B rows, 16B-aligned, 2-way-free banks
#define HBP  136    // Eb/Sb pitch (u16): 272 B rows
#define LT   106496 // packed edge weights per layer (u16)
#define LN_  49152  // packed node weights per layer (u16)
#define NG   196608 // offset of global node weights in packn

typedef unsigned short u16;
typedef short bf16x8 __attribute__((ext_vector_type(8)));
typedef float f32x4 __attribute__((ext_vector_type(4)));

__device__ __forceinline__ float sigmoidf_(float v){ return 1.0f/(1.0f + __expf(-v)); }
__device__ __forceinline__ float siluf_(float v){ return v * sigmoidf_(v); }
__device__ __forceinline__ u16 f2bf(float f){
  unsigned u = __float_as_uint(f);
  return (u16)((u + 0x7FFFu + ((u>>16)&1u)) >> 16);
}
__device__ __forceinline__ float bf2f(u16 v){ return __uint_as_float(((unsigned)v)<<16); }
__device__ __forceinline__ uint2 pack4(float a, float b, float c, float d){
  uint2 r;
  r.x = (unsigned)f2bf(a) | ((unsigned)f2bf(b)<<16);
  r.y = (unsigned)f2bf(c) | ((unsigned)f2bf(d)<<16);
  return r;
}

template<int ACT>
__device__ __forceinline__ float apply_act(float v){ return (ACT==1) ? siluf_(v) : v; }

// ---- MFMA helpers (use: tid, wrow, l15, q8, quad from scope) ----
// A-operand = weights (M=outcol), B-operand = activations (N=row/edge).
// D: row(quad*4+reg)=outcol-within-tile, col(l15)=edge -> thread owns 4 contiguous outcols.
#define STAGE_WT(GSRC, KPAD, K0) \
  _Pragma("unroll") \
  for (int i_=0;i_<4;i_++){ \
    int o_ = tid + i_*256; \
    int c_ = o_ >> 3, ko_ = (o_ & 7)*8; \
    *(uint4*)&Wt[c_][ko_] = *(const uint4*)((GSRC) + (size_t)c_*(KPAD) + (K0) + ko_); \
  }

#define STAGE_AB(ROWPTR) \
  _Pragma("unroll") \
  for (int i_=0;i_<2;i_++){ \
    int o_ = tid*2 + i_; \
    int r_ = o_ >> 3, ko_ = (o_ & 7)*8; \
    const u16* rp_ = (ROWPTR); \
    *(uint4*)&Ab[r_][ko_] = *(const uint4*)(rp_ + ko_); \
  }

#define STAGE_AF(FROWPTR) \
  _Pragma("unroll") \
  for (int i_=0;i_<2;i_++){ \
    int o_ = tid*2 + i_; \
    int r_ = o_ >> 3, ko_ = (o_ & 7)*8; \
    const float* rp_ = (FROWPTR); \
    float4 f0_ = *(const float4*)(rp_ + ko_); \
    float4 f1_ = *(const float4*)(rp_ + ko_ + 4); \
    uint4 pk_; \
    pk_.x = (unsigned)f2bf(f0_.x) | ((unsigned)f2bf(f0_.y)<<16); \
    pk_.y = (unsigned)f2bf(f0_.z) | ((unsigned)f2bf(f0_.w)<<16); \
    pk_.z = (unsigned)f2bf(f1_.x) | ((unsigned)f2bf(f1_.y)<<16); \
    pk_.w = (unsigned)f2bf(f1_.z) | ((unsigned)f2bf(f1_.w)<<16); \
    *(uint4*)&Ab[r_][ko_] = pk_; \
  }

#define MFMA_TILES(BBUF, KOFF, ACC) \
  _Pragma("unroll") \
  for (int ks_=0; ks_<KC; ks_+=32){ \
    bf16x8 bf_ = *(const bf16x8*)&BBUF[wrow + l15][(KOFF) + ks_ + q8]; \
    _Pragma("unroll") \
    for (int t_=0;t_<8;t_++){ \
      bf16x8 wf_ = *(const bf16x8*)&Wt[t_*16 + l15][ks_ + q8]; \
      ACC[t_] = __builtin_amdgcn_mfma_f32_16x16x32_bf16(wf_, bf_, ACC[t_], 0, 0, 0); \
    } \
  }

// ---------------------------------------------------------------- utility
__global__ void k_zero(float* __restrict__ p, int n){
  int i = blockIdx.x*256 + threadIdx.x; if (i < n) p[i] = 0.f;
}
__global__ void k_zero_i(int* __restrict__ p, int n){
  int i = blockIdx.x*256 + threadIdx.x; if (i < n) p[i] = 0;
}
__global__ void k_embed(const int* __restrict__ z, const float* __restrict__ emb,
                        float* __restrict__ x, u16* __restrict__ xb){
  int i = blockIdx.x*256 + threadIdx.x;
  int n = i >> 7, h = i & 127;
  float v = emb[z[n]*H + h];
  x[i] = v; xb[i] = f2bf(v);
}
__global__ void k_af(float* __restrict__ io, u16* __restrict__ ob){
  int i = blockIdx.x*256 + threadIdx.x;
  float v = io[i]*(1.0f/3.0f);
  io[i] = v; ob[i] = f2bf(v);
}

// ---------------------------------------------------------------- weight packing
__global__ void k_pack(const float* __restrict__ ee_w1, const float* __restrict__ ee_w2,
                       const float* __restrict__ msg_w1, const float* __restrict__ msg_w2,
                       const float* __restrict__ gate_w, u16* __restrict__ out){
  int idx = blockIdx.x*256 + threadIdx.x;
  int l = blockIdx.y;
  if (idx >= LT) return;
  u16* o = out + (size_t)l*LT;
  float v; int c, k;
  if (idx < 8192){            c = idx>>6;  k = idx&63;
    v = (k<RBF) ? ee_w1[(size_t)l*RBF*H + k*H + c] : 0.f; }
  else if (idx < 24576){ int j=idx-8192;  c=j>>7; k=j&127;
    v = ee_w2[(size_t)l*H*H + k*H + c]; }
  else if (idx < 73728){ int j=idx-24576; c=j/384; k=j%384;
    v = msg_w1[(size_t)l*3*H*H + k*H + c]; }
  else if (idx < 90112){ int j=idx-73728; c=j>>7; k=j&127;
    v = msg_w2[(size_t)l*H*H + k*H + c]; }
  else {                 int j=idx-90112; c=j>>7; k=j&127;
    v = gate_w[(size_t)l*H*H + k*H + c]; }
  o[idx] = f2bf(v);
}

__global__ void k_packn(const float* __restrict__ upd_w1, const float* __restrict__ upd_w2,
                        const float* __restrict__ ro_w1, const float* __restrict__ ro_w2,
                        const float* __restrict__ pn_w, const float* __restrict__ gp_w1,
                        u16* __restrict__ out){
  int idx = blockIdx.x*256 + threadIdx.x;
  if (idx >= NG + 65536) return;
  float v;
  if (idx < NG){
    int l = idx / LN_, j = idx % LN_;
    if (j < 32768){ int c = j>>8, k = j&255; v = upd_w1[(size_t)l*256*H + k*H + c]; }
    else { int j2 = j-32768; int c = j2>>7, k = j2&127; v = upd_w2[(size_t)l*H*H + k*H + c]; }
  } else {
    int j = idx - NG; int m = j >> 14; int j2 = j & 16383;
    int c = j2>>7, k = j2&127;
    const float* W = (m==0) ? ro_w1 : (m==1) ? ro_w2 : (m==2) ? pn_w : gp_w1;
    v = W[k*H + c];
  }
  out[idx] = f2bf(v);
}

// ---------------------------------------------------------------- edge sort by dst
__global__ void k_hist(const int* __restrict__ dstv, int* __restrict__ cnt){
  int e = blockIdx.x*256 + threadIdx.x;
  if (e < NE) atomicAdd(&cnt[dstv[e]], 1);
}
__global__ __launch_bounds__(1024)
void k_scan(int* __restrict__ cnt, int* __restrict__ start){
  __shared__ int ps[1024];
  int tid = threadIdx.x;
  int base = tid*16;
  int loc[16]; int s = 0;
#pragma unroll
  for (int i=0;i<16;i++){ loc[i] = s; s += cnt[base+i]; }
  ps[tid] = s; __syncthreads();
  for (int off=1; off<1024; off<<=1){
    int v = (tid>=off) ? ps[tid-off] : 0;
    __syncthreads();
    ps[tid] += v;
    __syncthreads();
  }
  int pre = (tid>0) ? ps[tid-1] : 0;
#pragma unroll
  for (int i=0;i<16;i++){ int v = pre + loc[i]; start[base+i] = v; cnt[base+i] = v; }
  if (tid == 0) start[NN] = NE;
}
__global__ void k_scatter(const int* __restrict__ srcv, const int* __restrict__ dstv,
                          int* __restrict__ cursor, int* __restrict__ src_s,
                          int* __restrict__ dst_s){
  int e = blockIdx.x*256 + threadIdx.x;
  if (e >= NE) return;
  int d = dstv[e];
  int p = atomicAdd(&cursor[d], 1);
  src_s[p] = srcv[e]; dst_s[p] = d;
}

// ---------------------------------------------------------------- FUSED edge pipeline (flipped MFMA)
__global__ __launch_bounds__(256)
void k_edge(const int* __restrict__ src_s, const int* __restrict__ dst_s,
            const float* __restrict__ pos, const float* __restrict__ widths,
            const u16* __restrict__ xb, const u16* __restrict__ pw,
            const float* __restrict__ b_ee1, const float* __restrict__ b_ee2,
            const float* __restrict__ b_m1, const float* __restrict__ b_m2,
            const float* __restrict__ b_g,
            float* __restrict__ aggr){
  __shared__ u16 Ab[TM][KP];
  __shared__ u16 Wt[H][KP];
  __shared__ u16 Eb[TM][HBP];
  __shared__ u16 Sb[TM][HBP];
  __shared__ int gdst[TM], gsrc[TM];
  __shared__ float dls[TM], cls[TM], gls[KC];
  __shared__ float bbA[H], bbB[H];

  const int tid = threadIdx.x;
  const int wave = tid>>6, l = tid&63, l15 = l&15, quad = l>>4;
  const int wrow = wave*16, q8 = quad*8;
  const int rowbase = blockIdx.x*TM;
  const int erow = wrow + l15;      // this thread's edge row (flipped layout)

  const u16* w_ee1 = pw;
  const u16* w_ee2 = pw + 8192;
  const u16* w_m1  = pw + 24576;
  const u16* w_m2  = pw + 73728;
  const u16* w_g   = pw + 90112;

  STAGE_WT(w_ee1, 64, 0)
  if (tid < TM){
    int e = rowbase + tid;
    int s = src_s[e], d = dst_s[e];
    gsrc[tid] = s; gdst[tid] = d;
    float dx = pos[3*d]-pos[3*s], dy = pos[3*d+1]-pos[3*s+1], dz = pos[3*d+2]-pos[3*s+2];
    float dist = sqrtf(dx*dx + dy*dy + dz*dz);
    dls[tid] = dist;
    cls[tid] = (dist < 5.0f) ? 0.5f*(__cosf(0.62831853f*dist) + 1.0f) : 0.0f;
  } else if (tid < TM+KC){
    int k = tid - TM;
    float w = (k < RBF) ? widths[k] : 1.0f;
    gls[k] = 1.0f/(2.0f*w*w);
  } else {
    int t = tid - 128;
    bbA[t] = b_ee1[t]; bbB[t] = b_ee2[t];
  }
  __syncthreads();
  { // RBF -> Ab
    int r = tid>>2, kb = (tid&3)*16;
    float dr = dls[r], cr = cls[r];
#pragma unroll
    for (int kk=0; kk<16; kk+=2){
      int k0 = kb+kk, k1 = kb+kk+1;
      float t0 = dr - 0.10204082f*(float)k0;
      float t1 = dr - 0.10204082f*(float)k1;
      float v0 = (k0 < RBF) ? __expf(-gls[k0]*t0*t0)*cr : 0.f;
      float v1 = (k1 < RBF) ? __expf(-gls[k1]*t1*t1)*cr : 0.f;
      *(unsigned*)&Ab[r][k0] = (unsigned)f2bf(v0) | ((unsigned)f2bf(v1)<<16);
    }
  }
  __syncthreads();

  f32x4 acc[8];
#pragma unroll
  for (int t=0;t<8;t++) acc[t] = (f32x4)(0.f);
  MFMA_TILES(Ab, 0, acc)                        // ee1 (K=64)
#pragma unroll
  for (int t=0;t<8;t++){                        // hidden silu -> Sb (8B vector writes)
    int co = t*16 + quad*4;
    *(uint2*)&Sb[erow][co] = pack4(
      siluf_(acc[t][0]+bbA[co]),   siluf_(acc[t][1]+bbA[co+1]),
      siluf_(acc[t][2]+bbA[co+2]), siluf_(acc[t][3]+bbA[co+3]));
  }
  __syncthreads();

#pragma unroll
  for (int t=0;t<8;t++) acc[t] = (f32x4)(0.f);
  for (int kc=0; kc<H; kc+=KC){                 // ee2 (K=128)
    STAGE_WT(w_ee2, 128, kc)
    __syncthreads();
    MFMA_TILES(Sb, kc, acc)
    __syncthreads();
  }
#pragma unroll
  for (int t=0;t<8;t++){                        // ee -> Eb
    int co = t*16 + quad*4;
    *(uint2*)&Eb[erow][co] = pack4(
      acc[t][0]+bbB[co],   acc[t][1]+bbB[co+1],
      acc[t][2]+bbB[co+2], acc[t][3]+bbB[co+3]);
  }

#pragma unroll
  for (int t=0;t<8;t++) acc[t] = (f32x4)(0.f);
  for (int kc6=0; kc6<6; kc6++){                // msg1 (K=384)
    if (kc6 < 2)      { const int kl = kc6*64;     STAGE_AB(xb + (size_t)gdst[r_]*H + kl) }
    else if (kc6 < 4) { const int kl = (kc6-2)*64; STAGE_AB(xb + (size_t)gsrc[r_]*H + kl) }
    STAGE_WT(w_m1, 384, kc6*64)
    if (kc6 == 0 && tid < H) bbA[tid] = b_m1[tid];
    __syncthreads();
    if (kc6 < 4) { MFMA_TILES(Ab, 0, acc) }
    else         { MFMA_TILES(Eb, (kc6-4)*64, acc) }
    __syncthreads();
  }
#pragma unroll
  for (int t=0;t<8;t++){                        // msg hidden silu -> Sb
    int co = t*16 + quad*4;
    *(uint2*)&Sb[erow][co] = pack4(
      siluf_(acc[t][0]+bbA[co]),   siluf_(acc[t][1]+bbA[co+1]),
      siluf_(acc[t][2]+bbA[co+2]), siluf_(acc[t][3]+bbA[co+3]));
  }
  __syncthreads();

  f32x4 accG[8];
#pragma unroll
  for (int t=0;t<8;t++){ acc[t] = (f32x4)(0.f); accG[t] = (f32x4)(0.f); }
  for (int kc=0; kc<H; kc+=KC){                 // msg2 (K=128)
    STAGE_WT(w_m2, 128, kc)
    if (kc == 0){ if (tid < H) bbB[tid] = b_m2[tid]; else bbA[tid-H] = b_g[tid-H]; }
    __syncthreads();
    MFMA_TILES(Sb, kc, acc)
    __syncthreads();
  }
  for (int kc=0; kc<H; kc+=KC){                 // gate (K=128)
    STAGE_WT(w_g, 128, kc)
    __syncthreads();
    MFMA_TILES(Eb, kc, accG)
    __syncthreads();
  }
#pragma unroll
  for (int t=0;t<8;t++){                        // gated message -> Sb
    int co = t*16 + quad*4;
    float m0 = acc[t][0]+bbB[co],   m1 = acc[t][1]+bbB[co+1];
    float m2 = acc[t][2]+bbB[co+2], m3 = acc[t][3]+bbB[co+3];
    float g0 = sigmoidf_(accG[t][0]+bbA[co]),   g1 = sigmoidf_(accG[t][1]+bbA[co+1]);
    float g2 = sigmoidf_(accG[t][2]+bbA[co+2]), g3 = sigmoidf_(accG[t][3]+bbA[co+3]);
    *(uint2*)&Sb[erow][co] = pack4(m0*g0, m1*g1, m2*g2, m3*g3);
  }
  __syncthreads();

  // segmented reduce over dst-sorted rows; atomic per run boundary
  { int col = tid & 127, half = tid >> 7;
    int rbeg = half*32, rend = rbeg + 32;
    float a = 0.f; int cur = gdst[rbeg];
    for (int r=rbeg; r<rend; r++){
      int d = gdst[r];
      if (d != cur){ atomicAdd(&aggr[(size_t)cur*H + col], a); a = 0.f; cur = d; }
      a += bf2f(Sb[r][col]);
    }
    atomicAdd(&aggr[(size_t)cur*H + col], a);
  }
}

// ---------------------------------------------------------------- node MFMA kernels
// upd1: concat(aggr f32, xb bf16) @ W (K=256) + b, silu -> bf16
__global__ __launch_bounds__(256)
void k_upd1(const float* __restrict__ aggr, const u16* __restrict__ xb,
            const u16* __restrict__ Wp, const float* __restrict__ bias,
            u16* __restrict__ outb){
  __shared__ u16 Ab[TM][KP];
  __shared__ u16 Wt[H][KP];
  __shared__ float bls[H];
  const int tid = threadIdx.x;
  const int wave = tid>>6, l = tid&63, l15 = l&15, quad = l>>4;
  const int wrow = wave*16, q8 = quad*8;
  const int rowbase = blockIdx.x*TM;
  if (tid < H) bls[tid] = bias[tid];
  f32x4 acc[8];
#pragma unroll
  for (int t=0;t<8;t++) acc[t] = (f32x4)(0.f);
  for (int kc=0; kc<256; kc+=KC){
    __syncthreads();
    if (kc < 128) { STAGE_AF(aggr + (size_t)(rowbase + r_)*H + kc) }
    else          { STAGE_AB(xb + (size_t)(rowbase + r_)*H + (kc-128)) }
    STAGE_WT(Wp, 256, kc)
    __syncthreads();
    MFMA_TILES(Ab, 0, acc)
  }
  const int node = rowbase + wrow + l15;
#pragma unroll
  for (int t=0;t<8;t++){
    int co = t*16 + quad*4;
    *(uint2*)&outb[(size_t)node*H + co] = pack4(
      siluf_(acc[t][0]+bls[co]),   siluf_(acc[t][1]+bls[co+1]),
      siluf_(acc[t][2]+bls[co+2]), siluf_(acc[t][3]+bls[co+3]));
  }
}

// upd2 + residual + LayerNorm; writes x f32, xb bf16, optional sumf +=
template<int ADDSUM>
__global__ __launch_bounds__(256)
void k_upd2_ln(const u16* __restrict__ hnb, const u16* __restrict__ Wp,
               const float* __restrict__ b2, const float* __restrict__ lng,
               const float* __restrict__ lnb, float* __restrict__ x,
               float* __restrict__ sumf, u16* __restrict__ xb){
  __shared__ u16 Ab[TM][KP];
  __shared__ u16 Wt[H][KP];
  __shared__ float bls[H], lgs[H], lbs[H];
  const int tid = threadIdx.x;
  const int wave = tid>>6, l = tid&63, l15 = l&15, quad = l>>4;
  const int wrow = wave*16, q8 = quad*8;
  const int rowbase = blockIdx.x*TM;
  if (tid < H){ bls[tid] = b2[tid]; lgs[tid] = lng[tid]; }
  else lbs[tid-H] = lnb[tid-H];
  f32x4 acc[8];
#pragma unroll
  for (int t=0;t<8;t++) acc[t] = (f32x4)(0.f);
  for (int kc=0; kc<H; kc+=KC){
    __syncthreads();
    STAGE_AB(hnb + (size_t)(rowbase + r_)*H + kc)
    STAGE_WT(Wp, 128, kc)
    __syncthreads();
    MFMA_TILES(Ab, 0, acc)
  }
  const int node = rowbase + wrow + l15;
  const size_t ro = (size_t)node*H;
  float y[8][4]; float s = 0.f, ss = 0.f;
#pragma unroll
  for (int t=0;t<8;t++){
    int co = t*16 + quad*4;
    float4 xv = *(const float4*)&x[ro + co];
    y[t][0] = xv.x + acc[t][0] + bls[co];
    y[t][1] = xv.y + acc[t][1] + bls[co+1];
    y[t][2] = xv.z + acc[t][2] + bls[co+2];
    y[t][3] = xv.w + acc[t][3] + bls[co+3];
#pragma unroll
    for (int r=0;r<4;r++){ s += y[t][r]; ss += y[t][r]*y[t][r]; }
  }
  s  += __shfl_xor(s, 16);  s  += __shfl_xor(s, 32);
  ss += __shfl_xor(ss, 16); ss += __shfl_xor(ss, 32);
  float mean = s*(1.0f/H);
  float var  = ss*(1.0f/H) - mean*mean;
  float inv  = rsqrtf(var + 1e-5f);
#pragma unroll
  for (int t=0;t<8;t++){
    int co = t*16 + quad*4;
    float4 o;
    o.x = (y[t][0]-mean)*inv*lgs[co]   + lbs[co];
    o.y = (y[t][1]-mean)*inv*lgs[co+1] + lbs[co+1];
    o.z = (y[t][2]-mean)*inv*lgs[co+2] + lbs[co+2];
    o.w = (y[t][3]-mean)*inv*lgs[co+3] + lbs[co+3];
    *(float4*)&x[ro + co] = o;
    if (ADDSUM){
      float4 sf = *(const float4*)&sumf[ro + co];
      sf.x += o.x; sf.y += o.y; sf.z += o.z; sf.w += o.w;
      *(float4*)&sumf[ro + co] = sf;
    }
    *(uint2*)&xb[ro + co] = pack4(o.x, o.y, o.z, o.w);
  }
}

// generic node GEMM K=128: A bf16 -> (act) -> f32 and/or bf16 out
template<int ACT, int OUTF32, int OUTBF>
__global__ __launch_bounds__(256)
void k_ngemm(const u16* __restrict__ A, const u16* __restrict__ Wp,
             const float* __restrict__ bias, float* __restrict__ outf,
             u16* __restrict__ outb){
  __shared__ u16 Ab[TM][KP];
  __shared__ u16 Wt[H][KP];
  __shared__ float bls[H];
  const int tid = threadIdx.x;
  const int wave = tid>>6, l = tid&63, l15 = l&15, quad = l>>4;
  const int wrow = wave*16, q8 = quad*8;
  const int rowbase = blockIdx.x*TM;
  if (tid < H) bls[tid] = bias[tid];
  f32x4 acc[8];
#pragma unroll
  for (int t=0;t<8;t++) acc[t] = (f32x4)(0.f);
  for (int kc=0; kc<H; kc+=KC){
    __syncthreads();
    STAGE_AB(A + (size_t)(rowbase + r_)*H + kc)
    STAGE_WT(Wp, 128, kc)
    __syncthreads();
    MFMA_TILES(Ab, 0, acc)
  }
  const int node = rowbase + wrow + l15;
#pragma unroll
  for (int t=0;t<8;t++){
    int co = t*16 + quad*4;
    float v0 = apply_act<ACT>(acc[t][0]+bls[co]);
    float v1 = apply_act<ACT>(acc[t][1]+bls[co+1]);
    float v2 = apply_act<ACT>(acc[t][2]+bls[co+2]);
    float v3 = apply_act<ACT>(acc[t][3]+bls[co+3]);
    if (OUTF32){
      float4 o; o.x=v0; o.y=v1; o.z=v2; o.w=v3;
      *(float4*)&outf[(size_t)node*H + co] = o;
    }
    if (OUTBF) *(uint2*)&outb[(size_t)node*H + co] = pack4(v0,v1,v2,v3);
  }
}

// gate score: tanh(ae@W1+b1)@w2 + b2 -> g[node]
__global__ __launch_bounds__(256)
void k_gscore(const u16* __restrict__ aeb, const u16* __restrict__ Wp,
              const float* __restrict__ b1, const float* __restrict__ w2,
              const float* __restrict__ b2, float* __restrict__ g){
  __shared__ u16 Ab[TM][KP];
  __shared__ u16 Wt[H][KP];
  __shared__ float bls[H], w2s[H];
  const int tid = threadIdx.x;
  const int wave = tid>>6, l = tid&63, l15 = l&15, quad = l>>4;
  const int wrow = wave*16, q8 = quad*8;
  const int rowbase = blockIdx.x*TM;
  if (tid < H) bls[tid] = b1[tid];
  else w2s[tid-H] = w2[tid-H];
  f32x4 acc[8];
#pragma unroll
  for (int t=0;t<8;t++) acc[t] = (f32x4)(0.f);
  for (int kc=0; kc<H; kc+=KC){
    __syncthreads();
    STAGE_AB(aeb + (size_t)(rowbase + r_)*H + kc)
    STAGE_WT(Wp, 128, kc)
    __syncthreads();
    MFMA_TILES(Ab, 0, acc)
  }
  float p = 0.f;
#pragma unroll
  for (int t=0;t<8;t++){
    int co = t*16 + quad*4;
#pragma unroll
    for (int r=0;r<4;r++) p = fmaf(tanhf(acc[t][r]+bls[co+r]), w2s[co+r], p);
  }
  p += __shfl_xor(p, 16); p += __shfl_xor(p, 32);
  if (quad == 0) g[rowbase + wrow + l15] = p + b2[0];
}

// ---------------------------------------------------------------- pooling
__global__ void k_start(const int* __restrict__ batch, int* __restrict__ start){
  int b = threadIdx.x;
  if (b > NB) return;
  if (b == NB){ start[NB] = NN; return; }
  int lo = 0, hi = NN;
  while (lo < hi){ int mid = (lo+hi) >> 1; if (batch[mid] < b) lo = mid+1; else hi = mid; }
  start[b] = lo;
}

__global__ __launch_bounds__(256)
void k_pool(const int* __restrict__ start, const float* __restrict__ g,
            float* __restrict__ exb, const u16* __restrict__ hb,
            float* __restrict__ out){
  const int b = blockIdx.x;
  const int s = start[b], e = start[b+1];
  const int tid = threadIdx.x;
  __shared__ float red[4];
  __shared__ float s_gmax, s_den;
  __shared__ float part[2][H];

  float mx = -1e30f;
  for (int n = s + tid; n < e; n += 256) mx = fmaxf(mx, g[n]);
#pragma unroll
  for (int m=32;m>=1;m>>=1) mx = fmaxf(mx, __shfl_xor(mx, m, 64));
  if ((tid & 63) == 0) red[tid >> 6] = mx;
  __syncthreads();
  if (tid == 0){
    float v = fmaxf(fmaxf(red[0],red[1]), fmaxf(red[2],red[3]));
    s_gmax = (e > s) ? v : 0.0f;
  }
  __syncthreads();
  const float gmax = s_gmax;

  float sum = 0.f;
  for (int n = s + tid; n < e; n += 256){
    float ex = __expf(g[n] - gmax);
    exb[n] = ex;
    sum += ex;
  }
#pragma unroll
  for (int m=32;m>=1;m>>=1) sum += __shfl_xor(sum, m, 64);
  if ((tid & 63) == 0) red[tid >> 6] = sum;
  __syncthreads();
  if (tid == 0) s_den = red[0]+red[1]+red[2]+red[3];
  __syncthreads();
  const float den = s_den;

  const int col = tid & 127, rg = tid >> 7;
  float acc = 0.f;
  for (int n = s + rg; n < e; n += 2) acc = fmaf(exb[n], bf2f(hb[(size_t)n*H + col]), acc);
  part[rg][col] = acc;
  __syncthreads();
  if (tid < H){
    float v = part[0][tid] + part[1][tid];
    out[b*H + tid] = (den > 0.f) ? v/den : 0.0f;
  }
}

// ================================================================ host
extern "C" void kernel_launch(void* const* d_in, const int* in_sizes, int n_in,
                              void* d_out, int out_size, void* d_ws, size_t ws_size,
                              hipStream_t stream){
  const int*   Z      = (const int*)  d_in[0];
  const float* pos    = (const float*)d_in[1];
  const int*   batch  = (const int*)  d_in[2];
  const int*   ei     = (const int*)  d_in[3];
  const float* embed  = (const float*)d_in[4];
  const float* widths = (const float*)d_in[5];
  const float* ee_w1  = (const float*)d_in[6];
  const float* ee_b1  = (const float*)d_in[7];
  const float* ee_w2  = (const float*)d_in[8];
  const float* ee_b2  = (const float*)d_in[9];
  const float* msg_w1 = (const float*)d_in[10];
  const float* msg_b1 = (const float*)d_in[11];
  const float* msg_w2 = (const float*)d_in[12];
  const float* msg_b2 = (const float*)d_in[13];
  const float* gate_w = (const float*)d_in[14];
  const float* gate_b = (const float*)d_in[15];
  const float* upd_w1 = (const float*)d_in[16];
  const float* upd_b1 = (const float*)d_in[17];
  const float* upd_w2 = (const float*)d_in[18];
  const float* upd_b2 = (const float*)d_in[19];
  const float* ln_g   = (const float*)d_in[20];
  const float* ln_b   = (const float*)d_in[21];
  const float* gp_w1  = (const float*)d_in[22];
  const float* gp_b1  = (const float*)d_in[23];
  const float* gp_w2  = (const float*)d_in[24];
  const float* gp_b2  = (const float*)d_in[25];
  const float* pn_w   = (const float*)d_in[26];
  const float* pn_b   = (const float*)d_in[27];
  const float* ro_w1  = (const float*)d_in[28];
  const float* ro_b1  = (const float*)d_in[29];
  const float* ro_w2  = (const float*)d_in[30];
  const float* ro_b2  = (const float*)d_in[31];

  const int* srcv = ei;
  const int* dstv = ei + NE;

  // ---- workspace carve (64B-aligned) — ~32 MB total
  char* p0 = (char*)d_ws;
  char* p = p0;
  auto carve = [&](size_t bytes)->char*{ char* q = p; p += (bytes + 63) & ~(size_t)63; return q; };
  float* x     = (float*)carve((size_t)NH*4);
  float* aggr  = (float*)carve((size_t)NH*4);
  float* gsc   = (float*)carve((size_t)NN*4);
  float* exb   = (float*)carve((size_t)NN*4);
  int*   startb  = (int*)carve((size_t)(NB+2)*4);
  int*   estart  = (int*)carve((size_t)(NN+1)*4);
  int*   ecursor = (int*)carve((size_t)NN*4);
  int*   src_s   = (int*)carve((size_t)NE*4);
  int*   dst_s   = (int*)carve((size_t)NE*4);
  u16*   xb      = (u16*)carve((size_t)NH*2);
  u16*   packw   = (u16*)carve((size_t)4*LT*2);
  u16*   packn   = (u16*)carve((size_t)(NG+65536)*2);
  u16*   nb1     = (u16*)carve((size_t)NH*2);
  u16*   nb2     = (u16*)carve((size_t)NH*2);

  float* out_af  = (float*)d_out;     // running sum of last-3 feats, then /3
  float* out_ae  = out_af + NH;
  float* out_gaf = out_ae + NH;

  // ---- once-per-call prep
  k_pack<<<dim3((LT+255)/256, 4), 256, 0, stream>>>(ee_w1, ee_w2, msg_w1, msg_w2, gate_w, packw);
  k_packn<<<(NG+65536+255)/256, 256, 0, stream>>>(upd_w1, upd_w2, ro_w1, ro_w2, pn_w, gp_w1, packn);
  k_zero_i<<<(NN+255)/256, 256, 0, stream>>>(ecursor, NN);
  k_hist<<<NE/256, 256, 0, stream>>>(dstv, ecursor);
  k_scan<<<1, 1024, 0, stream>>>(ecursor, estart);
  k_scatter<<<NE/256, 256, 0, stream>>>(srcv, dstv, ecursor, src_s, dst_s);
  k_embed<<<NH/256, 256, 0, stream>>>(Z, embed, x, xb);
  k_zero<<<NH/256, 256, 0, stream>>>(out_af, NH);

  for (int l=0; l<4; l++){
    const u16* pw  = packw + (size_t)l*LT;
    const u16* pwn = packn + (size_t)l*LN_;
    k_zero<<<NH/256, 256, 0, stream>>>(aggr, NH);
    k_edge<<<NE/TM, 256, 0, stream>>>(src_s, dst_s, pos, widths, xb, pw,
                                      ee_b1 + l*H, ee_b2 + l*H, msg_b1 + l*H,
                                      msg_b2 + l*H, gate_b + l*H, aggr);
    k_upd1<<<NN/TM, 256, 0, stream>>>(aggr, xb, pwn, upd_b1 + l*H, nb1);
    if (l == 0)
      k_upd2_ln<0><<<NN/TM, 256, 0, stream>>>(nb1, pwn + 32768, upd_b2 + l*H,
                                              ln_g + l*H, ln_b + l*H, x, out_af, xb);
    else
      k_upd2_ln<1><<<NN/TM, 256, 0, stream>>>(nb1, pwn + 32768, upd_b2 + l*H,
                                              ln_g + l*H, ln_b + l*H, x, out_af, xb);
  }

  k_af<<<NH/256, 256, 0, stream>>>(out_af, nb1);
  k_ngemm<1,0,1><<<NN/TM, 256, 0, stream>>>(nb1, packn + NG,         ro_b1, nullptr, nb2);
  k_ngemm<0,1,1><<<NN/TM, 256, 0, stream>>>(nb2, packn + NG + 16384, ro_b2, out_ae, nb1);
  k_gscore<<<NN/TM, 256, 0, stream>>>(nb1, packn + NG + 49152, gp_b1, gp_w2, gp_b2, gsc);
  k_ngemm<1,0,1><<<NN/TM, 256, 0, stream>>>(nb1, packn + NG + 32768, pn_b, nullptr, nb2);
  k_start<<<1, 64, 0, stream>>>(batch, startb);
  k_pool<<<NB, 256, 0, stream>>>(startb, gsc, exb, nb2, out_gaf);
}